// Round 3
// baseline (740.971 us; speedup 1.0000x reference)
//
#include <hip/hip_runtime.h>
#include <hip/hip_bf16.h>
#include <math.h>

typedef __hip_bfloat16 bf16;

#define B_SZ 4
#define SEQ  4096
#define DM   256
#define NST  16
#define NCHK 64
#define LC   (SEQ/NCHK)      /* 64 */
#define MT   (B_SZ*SEQ)      /* 16384 rows of (b,l) */

__device__ __forceinline__ float silu_f(float v){ return v / (1.f + __expf(-v)); }

// ---------------------------------------------------------------------------
// Generic tiled GEMM: Out[M,N] = (A[M,K] (optionally * A2[M,K])) @ Bw[N,K]^T
// All fp32.
// EPI 0: store fp32. EPI 1: store fp32 + 2*bias[n]. EPI 2: fp32 store of
//        (acc * zc[m,n] * cwx[n] + bias[n])   (final fused epilogue)
// ---------------------------------------------------------------------------
template<int EPI, bool A2M>
__global__ __launch_bounds__(256)
void gemm_k(const float* __restrict__ A, const float* __restrict__ A2,
            const float* __restrict__ Bw, void* __restrict__ Out,
            int M, int N, int K, int lda,
            const float* __restrict__ bias, const float* __restrict__ zc,
            const float* __restrict__ cwx)
{
  constexpr int TM = 64, TN = 64, TK = 16;
  __shared__ __align__(16) float As[TK][TM + 4];
  __shared__ __align__(16) float Bs[TK][TN + 4];
  const int tid = threadIdx.x;
  const int tn = tid & 15, tm = tid >> 4;
  const int n0 = blockIdx.x * TN, m0 = blockIdx.y * TM;
  float acc[4][4] = {};
  const int ml = tid >> 2;          // 0..63 (row within tile)
  const int kq = (tid & 3) << 2;    // 0,4,8,12 (k quad)

  for (int k0 = 0; k0 < K; k0 += TK) {
    { // stage A (64 rows x 16 k), vectorized 4-wide
      size_t off = (size_t)(m0 + ml) * lda + k0 + kq;
      float4 q = *(const float4*)(A + off);
      float v0 = q.x, v1 = q.y, v2 = q.z, v3 = q.w;
      if constexpr (A2M) {
        float4 p = *(const float4*)(A2 + off);
        v0 *= p.x; v1 *= p.y; v2 *= p.z; v3 *= p.w;
      }
      As[kq+0][ml] = v0; As[kq+1][ml] = v1; As[kq+2][ml] = v2; As[kq+3][ml] = v3;
    }
    { // stage B (64 n-rows x 16 k), guard N (N=48 case)
      float v0 = 0.f, v1 = 0.f, v2 = 0.f, v3 = 0.f;
      if (n0 + ml < N) {
        float4 q = *(const float4*)(Bw + (size_t)(n0 + ml) * K + k0 + kq);
        v0 = q.x; v1 = q.y; v2 = q.z; v3 = q.w;
      }
      Bs[kq+0][ml] = v0; Bs[kq+1][ml] = v1; Bs[kq+2][ml] = v2; Bs[kq+3][ml] = v3;
    }
    __syncthreads();
    #pragma unroll
    for (int k = 0; k < TK; k++) {
      float4 av = *(const float4*)&As[k][tm << 2];
      float4 bv = *(const float4*)&Bs[k][tn << 2];
      float a[4] = {av.x, av.y, av.z, av.w};
      float b[4] = {bv.x, bv.y, bv.z, bv.w};
      #pragma unroll
      for (int i = 0; i < 4; i++)
        #pragma unroll
        for (int j = 0; j < 4; j++)
          acc[i][j] = fmaf(a[i], b[j], acc[i][j]);
    }
    __syncthreads();
  }

  #pragma unroll
  for (int i = 0; i < 4; i++) {
    int m = m0 + (tm << 2) + i;
    #pragma unroll
    for (int j = 0; j < 4; j++) {
      int n = n0 + (tn << 2) + j;
      if (n < N) {
        float v = acc[i][j];
        if constexpr (EPI == 0) {
          ((float*)Out)[(size_t)m * N + n] = v;
        } else if constexpr (EPI == 1) {
          ((float*)Out)[(size_t)m * N + n] = v + 2.f * bias[n];
        } else {
          float o = v * zc[(size_t)m * N + n] * cwx[n] + bias[n];
          ((float*)Out)[(size_t)m * N + n] = o;
        }
      }
    }
  }
}

// ---------------------------------------------------------------------------
// Depthwise conv (k=1 / k=3 / k=5, 'same', cross-correlation) + SiLU.
// Input xyz is (b, l, 768) fp32; outputs xc/yc/zc are (b, l, 256) fp32.
// 768 = 3*256 so each 256-thread block is entirely within one of x/y/z.
// ---------------------------------------------------------------------------
__global__ __launch_bounds__(256)
void conv_silu_k(const float* __restrict__ xyz,
                 const float* __restrict__ wx, const float* __restrict__ bx,
                 const float* __restrict__ wy, const float* __restrict__ by,
                 const float* __restrict__ wz, const float* __restrict__ bz,
                 float* __restrict__ xc, float* __restrict__ yc,
                 float* __restrict__ zc)
{
  size_t idx = (size_t)blockIdx.x * 256 + threadIdx.x;   // over MT*768
  int o = (int)(idx % 768);
  size_t ml = idx / 768;                 // b*SEQ + l
  int l = (int)(ml % SEQ);
  size_t brow = ml - (size_t)l;          // b*SEQ
  if (o < 256) {
    float v = xyz[idx] * wx[o] + bx[o];
    xc[ml * 256 + o] = silu_f(v);
  } else if (o < 512) {
    int d = o - 256;
    float v = by[d];
    #pragma unroll
    for (int t = 0; t < 3; t++) {
      int ll = l + t - 1;
      if (ll >= 0 && ll < SEQ) v += xyz[(brow + ll) * 768 + o] * wy[d * 3 + t];
    }
    yc[ml * 256 + d] = silu_f(v);
  } else {
    int d = o - 512;
    float v = bz[d];
    #pragma unroll
    for (int t = 0; t < 5; t++) {
      int ll = l + t - 2;
      if (ll >= 0 && ll < SEQ) v += xyz[(brow + ll) * 768 + o] * wz[d * 5 + t];
    }
    zc[ml * 256 + d] = silu_f(v);
  }
}

// ---------------------------------------------------------------------------
// Chunked selective scan. Thread = (d_local, n); block = (chunk, d_group, b).
// Pass A (PASSC=false): from h=0, compute chunk-local final state + decay
//   product. Pass C (PASSC=true): start from Hstart, emit y.
// ---------------------------------------------------------------------------
template<bool PASSC>
__global__ __launch_bounds__(256)
void scan_k(const float* __restrict__ xc,     // u, (MT,256)
            const float* __restrict__ dtv,    // (MT,256), includes 2*bias
            const float* __restrict__ xdbl,   // (MT,48): [dt_r | B | C]
            const float* __restrict__ A_log,
            const float* __restrict__ Dp,
            const float* __restrict__ Hstart, // pass C input
            float* __restrict__ Pbuf, float* __restrict__ hfbuf, // pass A out
            float* __restrict__ pout)         // pass C out, (MT,256)
{
  __shared__ float u_s[LC][16], dt_s[LC][16], Bc_s[LC][16], Cc_s[LC][16];
  __shared__ float y_s[16][LC + 1];
  const int tid = threadIdx.x;
  const int n = tid & 15, dl = tid >> 4;     // state idx, channel-in-group
  const int ch = blockIdx.x;                 // chunk 0..63
  const int d0 = blockIdx.y * 16;            // channel group
  const int b  = blockIdx.z;
  const int d  = d0 + dl;
  const int t0 = ch * LC;
  const size_t brow = (size_t)b * SEQ;

  #pragma unroll
  for (int i = 0; i < 4; i++) {              // cooperative coalesced staging
    int idx = tid + i * 256;
    int t = idx >> 4, dd = idx & 15;
    size_t row = brow + t0 + t;
    u_s [t][dd] = xc  [row * 256 + d0 + dd];
    dt_s[t][dd] = dtv [row * 256 + d0 + dd];
    Bc_s[t][dd] = xdbl[row * 48 + 16 + dd];
    Cc_s[t][dd] = xdbl[row * 48 + 32 + dd];
  }
  __syncthreads();

  const float A_dn = -__expf(A_log[d * NST + n]);
  const float Dd = Dp[d];
  const size_t cidx = (((size_t)b * DM + d) * NST + n) * NCHK + ch;

  float h = PASSC ? Hstart[cidx] : 0.f;
  float P = 1.f;
  for (int t = 0; t < LC; t++) {
    float draw = dt_s[t][dl];
    float delta = (draw > 15.f) ? draw : log1pf(__expf(draw));  // softplus
    float dA = __expf(delta * A_dn);
    float uu = u_s[t][dl];
    float dBu = delta * Bc_s[t][n] * uu;
    h = dA * h + dBu;
    if constexpr (!PASSC) {
      P *= dA;
    } else {
      float yv = h * Cc_s[t][n];
      #pragma unroll
      for (int off = 1; off < 16; off <<= 1) yv += __shfl_xor(yv, off);
      if (n == 0) y_s[dl][t] = yv + Dd * uu;
    }
  }

  if constexpr (!PASSC) {
    Pbuf[cidx] = P;
    hfbuf[cidx] = h;
  } else {
    __syncthreads();
    #pragma unroll
    for (int i = 0; i < 4; i++) {            // coalesced writeback
      int idx = tid + i * 256;
      int t = idx >> 4, dd = idx & 15;
      pout[(brow + t0 + t) * 256 + d0 + dd] = y_s[dd][t];
    }
  }
}

// serial combine across the 64 chunks; one thread per (b,d,n) chain
__global__ __launch_bounds__(256)
void scan_mid_k(const float* __restrict__ Pbuf, const float* __restrict__ hfbuf,
                float* __restrict__ Hstart)
{
  int tid = blockIdx.x * 256 + threadIdx.x;   // 0..16383
  size_t base = (size_t)tid * NCHK;
  float H = 0.f;
  for (int c = 0; c < NCHK; c++) {
    Hstart[base + c] = H;
    H = Pbuf[base + c] * H + hfbuf[base + c];
  }
}

// ---------------------------------------------------------------------------
extern "C" void kernel_launch(void* const* d_in, const int* in_sizes, int n_in,
                              void* d_out, int out_size, void* d_ws, size_t ws_size,
                              hipStream_t stream)
{
  const float* hs    = (const float*)d_in[0];
  const float* w_in  = (const float*)d_in[1];
  const float* w_xp  = (const float*)d_in[2];
  const float* w_dt  = (const float*)d_in[3];
  const float* b_dt  = (const float*)d_in[4];
  const float* A_log = (const float*)d_in[5];
  const float* Dp    = (const float*)d_in[6];
  const float* w_o1  = (const float*)d_in[7];
  const float* cwx   = (const float*)d_in[8];
  const float* cbx   = (const float*)d_in[9];
  const float* cwy   = (const float*)d_in[10];
  const float* cby   = (const float*)d_in[11];
  const float* cwz   = (const float*)d_in[12];
  const float* cbz   = (const float*)d_in[13];

  float* ws = (float*)d_ws;
  // region A: xyz (dead after conv), then reused for scan-phase buffers
  float* xyz  = ws;                                   // MT*768
  float* xc   = ws  + (size_t)MT * 768;               // MT*256
  float* yc   = xc  + (size_t)MT * 256;               // MT*256
  float* zc   = yc  + (size_t)MT * 256;               // MT*256
  // reuse of region A (total 12,320,768 <= MT*768 = 12,582,912 floats):
  float* xdbl = ws;                                   // MT*48
  float* dtv  = xdbl + (size_t)MT * 48;               // MT*256
  float* pbuf = dtv  + (size_t)MT * 256;               // MT*256
  float* Pb   = pbuf + (size_t)MT * 256;              // 1,048,576
  float* hf   = Pb   + (size_t)B_SZ * DM * NST * NCHK;
  float* Hs   = hf   + (size_t)B_SZ * DM * NST * NCHK;

  dim3 blk(256);

  // K1: xyz[M,768] = hs @ in_proj_w^T
  gemm_k<0, false><<<dim3(768 / 64, MT / 64), blk, 0, stream>>>(
      hs, nullptr, w_in, xyz, MT, 768, 256, 256, nullptr, nullptr, nullptr);

  // K2: depthwise conv + SiLU -> xc, yc, zc  (b,l,d)
  conv_silu_k<<<dim3((MT * 768) / 256), blk, 0, stream>>>(
      xyz, cwx, cbx, cwy, cby, cwz, cbz, xc, yc, zc);

  // K3: x_dbl[M,48] = xc @ x_proj_w^T
  gemm_k<0, false><<<dim3(1, MT / 64), blk, 0, stream>>>(
      xc, nullptr, w_xp, xdbl, MT, 48, 256, 256, nullptr, nullptr, nullptr);

  // K4: dtv[M,256] = x_dbl[:, :16] @ dt_proj_w^T + 2*dt_proj_b
  gemm_k<1, false><<<dim3(256 / 64, MT / 64), blk, 0, stream>>>(
      xdbl, nullptr, w_dt, dtv, MT, 256, 16, 48, b_dt, nullptr, nullptr);

  // K5-7: chunked selective scan -> pbuf (b,l,d)
  scan_k<false><<<dim3(NCHK, DM / 16, B_SZ), blk, 0, stream>>>(
      xc, dtv, xdbl, A_log, Dp, nullptr, Pb, hf, nullptr);
  scan_mid_k<<<dim3((B_SZ * DM * NST) / 256), blk, 0, stream>>>(Pb, hf, Hs);
  scan_k<true><<<dim3(NCHK, DM / 16, B_SZ), blk, 0, stream>>>(
      xc, dtv, xdbl, A_log, Dp, Hs, nullptr, nullptr, pbuf);

  // K8: out = ((pbuf*yc) @ out_proj1_w^T) * zc * cwx + cbx   (fp32 store)
  gemm_k<2, true><<<dim3(256 / 64, MT / 64), blk, 0, stream>>>(
      pbuf, yc, w_o1, d_out, MT, 256, 256, 256, cbx, zc, cwx);
}

// Round 4
// 400.678 us; speedup vs baseline: 1.8493x; 1.8493x over previous
//
#include <hip/hip_runtime.h>
#include <hip/hip_bf16.h>
#include <math.h>

typedef __hip_bfloat16 bf16;

#define B_SZ 4
#define SEQ  4096
#define DM   256
#define NST  16
#define NCHK 64
#define LC   (SEQ/NCHK)      /* 64 */
#define MT   (B_SZ*SEQ)      /* 16384 rows of (b,l) */

__device__ __forceinline__ float silu_f(float v){ return v / (1.f + __expf(-v)); }
__device__ __forceinline__ float softplus_f(float v){
  return (v > 15.f) ? v : __logf(1.f + __expf(v));
}

// ---------------------------------------------------------------------------
// Generic tiled GEMM: Out[M,N] = (A[M,K] (optionally * A2[M,K])) @ Bw[N,K]^T
// All fp32.
// EPI 0: store fp32.
// EPI 2: fp32 store of (acc * zc[m,n] * cwx[n] + bias[n])  (final epilogue)
// EPI 3: fp32 store of softplus(acc + 2*bias[n])           (delta epilogue)
// ---------------------------------------------------------------------------
template<int EPI, bool A2M>
__global__ __launch_bounds__(256)
void gemm_k(const float* __restrict__ A, const float* __restrict__ A2,
            const float* __restrict__ Bw, void* __restrict__ Out,
            int M, int N, int K, int lda,
            const float* __restrict__ bias, const float* __restrict__ zc,
            const float* __restrict__ cwx)
{
  constexpr int TM = 64, TN = 64, TK = 16;
  __shared__ __align__(16) float As[TK][TM + 4];
  __shared__ __align__(16) float Bs[TK][TN + 4];
  const int tid = threadIdx.x;
  const int tn = tid & 15, tm = tid >> 4;
  const int n0 = blockIdx.x * TN, m0 = blockIdx.y * TM;
  float acc[4][4] = {};
  const int ml = tid >> 2;          // 0..63 (row within tile)
  const int kq = (tid & 3) << 2;    // 0,4,8,12 (k quad)

  for (int k0 = 0; k0 < K; k0 += TK) {
    { // stage A (64 rows x 16 k), vectorized 4-wide
      size_t off = (size_t)(m0 + ml) * lda + k0 + kq;
      float4 q = *(const float4*)(A + off);
      float v0 = q.x, v1 = q.y, v2 = q.z, v3 = q.w;
      if constexpr (A2M) {
        float4 p = *(const float4*)(A2 + off);
        v0 *= p.x; v1 *= p.y; v2 *= p.z; v3 *= p.w;
      }
      As[kq+0][ml] = v0; As[kq+1][ml] = v1; As[kq+2][ml] = v2; As[kq+3][ml] = v3;
    }
    { // stage B (64 n-rows x 16 k), guard N (N=48 case)
      float v0 = 0.f, v1 = 0.f, v2 = 0.f, v3 = 0.f;
      if (n0 + ml < N) {
        float4 q = *(const float4*)(Bw + (size_t)(n0 + ml) * K + k0 + kq);
        v0 = q.x; v1 = q.y; v2 = q.z; v3 = q.w;
      }
      Bs[kq+0][ml] = v0; Bs[kq+1][ml] = v1; Bs[kq+2][ml] = v2; Bs[kq+3][ml] = v3;
    }
    __syncthreads();
    #pragma unroll
    for (int k = 0; k < TK; k++) {
      float4 av = *(const float4*)&As[k][tm << 2];
      float4 bv = *(const float4*)&Bs[k][tn << 2];
      float a[4] = {av.x, av.y, av.z, av.w};
      float b[4] = {bv.x, bv.y, bv.z, bv.w};
      #pragma unroll
      for (int i = 0; i < 4; i++)
        #pragma unroll
        for (int j = 0; j < 4; j++)
          acc[i][j] = fmaf(a[i], b[j], acc[i][j]);
    }
    __syncthreads();
  }

  #pragma unroll
  for (int i = 0; i < 4; i++) {
    int m = m0 + (tm << 2) + i;
    #pragma unroll
    for (int j = 0; j < 4; j++) {
      int n = n0 + (tn << 2) + j;
      if (n < N) {
        float v = acc[i][j];
        if constexpr (EPI == 0) {
          ((float*)Out)[(size_t)m * N + n] = v;
        } else if constexpr (EPI == 2) {
          float o = v * zc[(size_t)m * N + n] * cwx[n] + bias[n];
          ((float*)Out)[(size_t)m * N + n] = o;
        } else {
          ((float*)Out)[(size_t)m * N + n] = softplus_f(v + 2.f * bias[n]);
        }
      }
    }
  }
}

// ---------------------------------------------------------------------------
// Depthwise conv (k=1 / k=3 / k=5, 'same', cross-correlation) + SiLU.
// Input xyz is (b, l, 768) fp32; outputs xc/yc/zc are (b, l, 256) fp32.
// ---------------------------------------------------------------------------
__global__ __launch_bounds__(256)
void conv_silu_k(const float* __restrict__ xyz,
                 const float* __restrict__ wx, const float* __restrict__ bx,
                 const float* __restrict__ wy, const float* __restrict__ by,
                 const float* __restrict__ wz, const float* __restrict__ bz,
                 float* __restrict__ xc, float* __restrict__ yc,
                 float* __restrict__ zc)
{
  size_t idx = (size_t)blockIdx.x * 256 + threadIdx.x;   // over MT*768
  int o = (int)(idx % 768);
  size_t ml = idx / 768;                 // b*SEQ + l
  int l = (int)(ml % SEQ);
  size_t brow = ml - (size_t)l;          // b*SEQ
  if (o < 256) {
    float v = xyz[idx] * wx[o] + bx[o];
    xc[ml * 256 + o] = silu_f(v);
  } else if (o < 512) {
    int d = o - 256;
    float v = by[d];
    #pragma unroll
    for (int t = 0; t < 3; t++) {
      int ll = l + t - 1;
      if (ll >= 0 && ll < SEQ) v += xyz[(brow + ll) * 768 + o] * wy[d * 3 + t];
    }
    yc[ml * 256 + d] = silu_f(v);
  } else {
    int d = o - 512;
    float v = bz[d];
    #pragma unroll
    for (int t = 0; t < 5; t++) {
      int ll = l + t - 2;
      if (ll >= 0 && ll < SEQ) v += xyz[(brow + ll) * 768 + o] * wz[d * 5 + t];
    }
    zc[ml * 256 + d] = silu_f(v);
  }
}

// ---------------------------------------------------------------------------
// Chunked selective scan. Thread = (d_local, n); block = (chunk, d_group, b).
// dtv now holds PRECOMPUTED delta = softplus(dt + 2*bias)  (from K4 EPI=3).
// Pass A (PASSC=false): from h=0, chunk-local final state + decay product.
// Pass C (PASSC=true): start from Hstart, emit y.
// ---------------------------------------------------------------------------
template<bool PASSC>
__global__ __launch_bounds__(256)
void scan_k(const float* __restrict__ xc,     // u, (MT,256)
            const float* __restrict__ dtv,    // delta, (MT,256)
            const float* __restrict__ xdbl,   // (MT,48): [dt_r | B | C]
            const float* __restrict__ A_log,
            const float* __restrict__ Dp,
            const float* __restrict__ Hstart, // pass C input
            float* __restrict__ Pbuf, float* __restrict__ hfbuf, // pass A out
            float* __restrict__ pout)         // pass C out, (MT,256)
{
  __shared__ float dt_s[LC][16], du_s[LC][16], Bc_s[LC][16];
  __shared__ float u_s[LC][16], Cc_s[LC][16];
  __shared__ float y_s[16][LC + 1];
  const int tid = threadIdx.x;
  const int n = tid & 15, dl = tid >> 4;     // state idx, channel-in-group
  const int ch = blockIdx.x;                 // chunk 0..63
  const int d0 = blockIdx.y * 16;            // channel group
  const int b  = blockIdx.z;
  const int d  = d0 + dl;
  const int t0 = ch * LC;
  const size_t brow = (size_t)b * SEQ;

  #pragma unroll
  for (int i = 0; i < 4; i++) {              // cooperative coalesced staging
    int idx = tid + i * 256;
    int t = idx >> 4, dd = idx & 15;
    size_t row = brow + t0 + t;
    float uval = xc [row * 256 + d0 + dd];
    float dval = dtv[row * 256 + d0 + dd];
    dt_s[t][dd] = dval;
    du_s[t][dd] = dval * uval;
    Bc_s[t][dd] = xdbl[row * 48 + 16 + dd];
    if constexpr (PASSC) {
      u_s [t][dd] = uval;
      Cc_s[t][dd] = xdbl[row * 48 + 32 + dd];
    }
  }
  __syncthreads();

  const float A_dn = -__expf(A_log[d * NST + n]);
  const float Dd = Dp[d];
  const size_t cidx = (((size_t)b * DM + d) * NST + n) * NCHK + ch;

  float h = PASSC ? Hstart[cidx] : 0.f;
  float P = 1.f;
  #pragma unroll 4
  for (int t = 0; t < LC; t++) {
    float delta = dt_s[t][dl];
    float dA = __expf(delta * A_dn);
    float dBu = du_s[t][dl] * Bc_s[t][n];
    h = fmaf(dA, h, dBu);
    if constexpr (!PASSC) {
      P *= dA;
    } else {
      float yv = h * Cc_s[t][n];
      #pragma unroll
      for (int off = 1; off < 16; off <<= 1) yv += __shfl_xor(yv, off);
      if (n == 0) y_s[dl][t] = fmaf(Dd, u_s[t][dl], yv);
    }
  }

  if constexpr (!PASSC) {
    Pbuf[cidx] = P;
    hfbuf[cidx] = h;
  } else {
    __syncthreads();
    #pragma unroll
    for (int i = 0; i < 4; i++) {            // coalesced writeback
      int idx = tid + i * 256;
      int t = idx >> 4, dd = idx & 15;
      pout[(brow + t0 + t) * 256 + d0 + dd] = y_s[dd][t];
    }
  }
}

// serial combine across the 64 chunks; one thread per (b,d,n) chain
__global__ __launch_bounds__(256)
void scan_mid_k(const float* __restrict__ Pbuf, const float* __restrict__ hfbuf,
                float* __restrict__ Hstart)
{
  int tid = blockIdx.x * 256 + threadIdx.x;   // 0..16383
  size_t base = (size_t)tid * NCHK;
  float H = 0.f;
  for (int c = 0; c < NCHK; c++) {
    Hstart[base + c] = H;
    H = Pbuf[base + c] * H + hfbuf[base + c];
  }
}

// ---------------------------------------------------------------------------
extern "C" void kernel_launch(void* const* d_in, const int* in_sizes, int n_in,
                              void* d_out, int out_size, void* d_ws, size_t ws_size,
                              hipStream_t stream)
{
  const float* hs    = (const float*)d_in[0];
  const float* w_in  = (const float*)d_in[1];
  const float* w_xp  = (const float*)d_in[2];
  const float* w_dt  = (const float*)d_in[3];
  const float* b_dt  = (const float*)d_in[4];
  const float* A_log = (const float*)d_in[5];
  const float* Dp    = (const float*)d_in[6];
  const float* w_o1  = (const float*)d_in[7];
  const float* cwx   = (const float*)d_in[8];
  const float* cbx   = (const float*)d_in[9];
  const float* cwy   = (const float*)d_in[10];
  const float* cby   = (const float*)d_in[11];
  const float* cwz   = (const float*)d_in[12];
  const float* cbz   = (const float*)d_in[13];

  float* ws = (float*)d_ws;
  // region A: xyz (dead after conv), then reused for scan-phase buffers
  float* xyz  = ws;                                   // MT*768
  float* xc   = ws  + (size_t)MT * 768;               // MT*256
  float* yc   = xc  + (size_t)MT * 256;               // MT*256
  float* zc   = yc  + (size_t)MT * 256;               // MT*256
  // reuse of region A (total 12,320,768 <= MT*768 = 12,582,912 floats):
  float* xdbl = ws;                                   // MT*48
  float* dtv  = xdbl + (size_t)MT * 48;               // MT*256 (delta)
  float* pbuf = dtv  + (size_t)MT * 256;              // MT*256
  float* Pb   = pbuf + (size_t)MT * 256;              // 1,048,576
  float* hf   = Pb   + (size_t)B_SZ * DM * NST * NCHK;
  float* Hs   = hf   + (size_t)B_SZ * DM * NST * NCHK;

  dim3 blk(256);

  // K1: xyz[M,768] = hs @ in_proj_w^T
  gemm_k<0, false><<<dim3(768 / 64, MT / 64), blk, 0, stream>>>(
      hs, nullptr, w_in, xyz, MT, 768, 256, 256, nullptr, nullptr, nullptr);

  // K2: depthwise conv + SiLU -> xc, yc, zc  (b,l,d)
  conv_silu_k<<<dim3((MT * 768) / 256), blk, 0, stream>>>(
      xyz, cwx, cbx, cwy, cby, cwz, cbz, xc, yc, zc);

  // K3: x_dbl[M,48] = xc @ x_proj_w^T
  gemm_k<0, false><<<dim3(1, MT / 64), blk, 0, stream>>>(
      xc, nullptr, w_xp, xdbl, MT, 48, 256, 256, nullptr, nullptr, nullptr);

  // K4: dtv[M,256] = softplus(x_dbl[:, :16] @ dt_proj_w^T + 2*dt_proj_b)
  gemm_k<3, false><<<dim3(256 / 64, MT / 64), blk, 0, stream>>>(
      xdbl, nullptr, w_dt, dtv, MT, 256, 16, 48, b_dt, nullptr, nullptr);

  // K5-7: chunked selective scan -> pbuf (b,l,d)
  scan_k<false><<<dim3(NCHK, DM / 16, B_SZ), blk, 0, stream>>>(
      xc, dtv, xdbl, A_log, Dp, nullptr, Pb, hf, nullptr);
  scan_mid_k<<<dim3((B_SZ * DM * NST) / 256), blk, 0, stream>>>(Pb, hf, Hs);
  scan_k<true><<<dim3(NCHK, DM / 16, B_SZ), blk, 0, stream>>>(
      xc, dtv, xdbl, A_log, Dp, Hs, nullptr, nullptr, pbuf);

  // K8: out = ((pbuf*yc) @ out_proj1_w^T) * zc * cwx + cbx   (fp32 store)
  gemm_k<2, true><<<dim3(256 / 64, MT / 64), blk, 0, stream>>>(
      pbuf, yc, w_o1, d_out, MT, 256, 256, 256, cbx, zc, cwx);
}

// Round 5
// 307.135 us; speedup vs baseline: 2.4125x; 1.3046x over previous
//
#include <hip/hip_runtime.h>
#include <hip/hip_bf16.h>
#include <math.h>

typedef __hip_bfloat16 bf16;
typedef __attribute__((ext_vector_type(8))) short bf16x8;
typedef __attribute__((ext_vector_type(4))) float f32x4;

#define B_SZ 4
#define SEQ  4096
#define DM   256
#define NST  16
#define NCHK 64
#define LC   (SEQ/NCHK)      /* 64 */
#define MT   (B_SZ*SEQ)      /* 16384 rows of (b,l) */

__device__ __forceinline__ float silu_f(float v){ return v / (1.f + __expf(-v)); }
__device__ __forceinline__ float softplus_f(float v){
  return (v > 15.f) ? v : __logf(1.f + __expf(v));
}
__device__ __forceinline__ short f2bf(float f){
  union { bf16 h; short s; } u; u.h = __float2bfloat16(f); return u.s;
}

// ---------------------------------------------------------------------------
// MFMA bf16 GEMM: Out[M,N] = (A[M,K] (* A2 elementwise)) @ Bw[N,K]^T, fp32 in/out.
// Block 256 thr = 4 waves (2x2), tile 128x128, BK=32. A/B staged fp32->bf16.
// Fragment layouts (m89/m120-verified): A/B operand row=lane&15, k=quad*8+j;
// C/D col=lane&15, row=quad*4+reg.
// EPI 0: plain fp32 store. EPI 2: (acc * zc[m,n] * cwx[n] + bias[n]).
// Requires M%128==0, N%128==0, K%32==0.
// ---------------------------------------------------------------------------
template<int EPI, bool A2M>
__global__ __launch_bounds__(256)
void mfma_gemm_k(const float* __restrict__ A, const float* __restrict__ A2,
                 const float* __restrict__ Bw, float* __restrict__ Out,
                 int N, int K,
                 const float* __restrict__ bias, const float* __restrict__ zc,
                 const float* __restrict__ cwx)
{
  constexpr int BM = 128, BN = 128, BK = 32, LDP = 40;  // pad 32->40 shorts
  __shared__ short As[BM * LDP];
  __shared__ short Bs[BN * LDP];
  const int tid  = threadIdx.x;
  const int wave = tid >> 6, lane = tid & 63;
  const int quad = lane >> 4, l16 = lane & 15;
  const int wm = (wave & 1) * 64, wn = (wave >> 1) * 64;
  const int m0 = blockIdx.y * BM, n0 = blockIdx.x * BN;
  const int srow = tid >> 3;            // 0..31 (row within 32-row pass)
  const int skq  = (tid & 7) * 4;       // k offset 0,4,..,28

  f32x4 acc[4][4] = {};

  for (int k0 = 0; k0 < K; k0 += BK) {
    #pragma unroll
    for (int p = 0; p < 4; p++) {
      int row = p * 32 + srow;
      size_t ga = (size_t)(m0 + row) * K + k0 + skq;
      float4 q = *(const float4*)(A + ga);
      if constexpr (A2M) {
        float4 r = *(const float4*)(A2 + ga);
        q.x *= r.x; q.y *= r.y; q.z *= r.z; q.w *= r.w;
      }
      short4 s; s.x = f2bf(q.x); s.y = f2bf(q.y); s.z = f2bf(q.z); s.w = f2bf(q.w);
      *(short4*)&As[row * LDP + skq] = s;
      size_t gb = (size_t)(n0 + row) * K + k0 + skq;
      float4 qb = *(const float4*)(Bw + gb);
      short4 sb; sb.x = f2bf(qb.x); sb.y = f2bf(qb.y); sb.z = f2bf(qb.z); sb.w = f2bf(qb.w);
      *(short4*)&Bs[row * LDP + skq] = sb;
    }
    __syncthreads();
    bf16x8 fa[4], fb[4];
    #pragma unroll
    for (int i = 0; i < 4; i++) {
      fa[i] = *(const bf16x8*)&As[(wm + i * 16 + l16) * LDP + quad * 8];
      fb[i] = *(const bf16x8*)&Bs[(wn + i * 16 + l16) * LDP + quad * 8];
    }
    #pragma unroll
    for (int i = 0; i < 4; i++)
      #pragma unroll
      for (int j = 0; j < 4; j++)
        acc[i][j] = __builtin_amdgcn_mfma_f32_16x16x32_bf16(fa[i], fb[j], acc[i][j], 0, 0, 0);
    __syncthreads();
  }

  #pragma unroll
  for (int i = 0; i < 4; i++) {
    #pragma unroll
    for (int j = 0; j < 4; j++) {
      int n = n0 + wn + j * 16 + l16;
      #pragma unroll
      for (int r = 0; r < 4; r++) {
        int m = m0 + wm + i * 16 + quad * 4 + r;
        float v = acc[i][j][r];
        if constexpr (EPI == 2)
          v = v * zc[(size_t)m * N + n] * cwx[n] + bias[n];
        Out[(size_t)m * N + n] = v;
      }
    }
  }
}

// ---------------------------------------------------------------------------
// Vector-fp32 tiled GEMM (kept for small shapes K3/K4).
// EPI 0: store fp32. EPI 3: fp32 store of softplus(acc + 2*bias[n]).
// ---------------------------------------------------------------------------
template<int EPI>
__global__ __launch_bounds__(256)
void gemm_k(const float* __restrict__ A,
            const float* __restrict__ Bw, void* __restrict__ Out,
            int M, int N, int K, int lda,
            const float* __restrict__ bias)
{
  constexpr int TM = 64, TN = 64, TK = 16;
  __shared__ __align__(16) float As[TK][TM + 4];
  __shared__ __align__(16) float Bs[TK][TN + 4];
  const int tid = threadIdx.x;
  const int tn = tid & 15, tm = tid >> 4;
  const int n0 = blockIdx.x * TN, m0 = blockIdx.y * TM;
  float acc[4][4] = {};
  const int ml = tid >> 2;          // 0..63
  const int kq = (tid & 3) << 2;    // 0,4,8,12

  for (int k0 = 0; k0 < K; k0 += TK) {
    {
      size_t off = (size_t)(m0 + ml) * lda + k0 + kq;
      float4 q = *(const float4*)(A + off);
      As[kq+0][ml] = q.x; As[kq+1][ml] = q.y; As[kq+2][ml] = q.z; As[kq+3][ml] = q.w;
    }
    {
      float v0 = 0.f, v1 = 0.f, v2 = 0.f, v3 = 0.f;
      if (n0 + ml < N) {
        float4 q = *(const float4*)(Bw + (size_t)(n0 + ml) * K + k0 + kq);
        v0 = q.x; v1 = q.y; v2 = q.z; v3 = q.w;
      }
      Bs[kq+0][ml] = v0; Bs[kq+1][ml] = v1; Bs[kq+2][ml] = v2; Bs[kq+3][ml] = v3;
    }
    __syncthreads();
    #pragma unroll
    for (int k = 0; k < TK; k++) {
      float4 av = *(const float4*)&As[k][tm << 2];
      float4 bv = *(const float4*)&Bs[k][tn << 2];
      float a[4] = {av.x, av.y, av.z, av.w};
      float b[4] = {bv.x, bv.y, bv.z, bv.w};
      #pragma unroll
      for (int i = 0; i < 4; i++)
        #pragma unroll
        for (int j = 0; j < 4; j++)
          acc[i][j] = fmaf(a[i], b[j], acc[i][j]);
    }
    __syncthreads();
  }

  #pragma unroll
  for (int i = 0; i < 4; i++) {
    int m = m0 + (tm << 2) + i;
    #pragma unroll
    for (int j = 0; j < 4; j++) {
      int n = n0 + (tn << 2) + j;
      if (n < N) {
        float v = acc[i][j];
        if constexpr (EPI == 0) {
          ((float*)Out)[(size_t)m * N + n] = v;
        } else {
          ((float*)Out)[(size_t)m * N + n] = softplus_f(v + 2.f * bias[n]);
        }
      }
    }
  }
}

// ---------------------------------------------------------------------------
// Depthwise conv (k=1 / k=3 / k=5, 'same', cross-correlation) + SiLU.
// ---------------------------------------------------------------------------
__global__ __launch_bounds__(256)
void conv_silu_k(const float* __restrict__ xyz,
                 const float* __restrict__ wx, const float* __restrict__ bx,
                 const float* __restrict__ wy, const float* __restrict__ by,
                 const float* __restrict__ wz, const float* __restrict__ bz,
                 float* __restrict__ xc, float* __restrict__ yc,
                 float* __restrict__ zc)
{
  size_t idx = (size_t)blockIdx.x * 256 + threadIdx.x;   // over MT*768
  int o = (int)(idx % 768);
  size_t ml = idx / 768;                 // b*SEQ + l
  int l = (int)(ml % SEQ);
  size_t brow = ml - (size_t)l;          // b*SEQ
  if (o < 256) {
    float v = xyz[idx] * wx[o] + bx[o];
    xc[ml * 256 + o] = silu_f(v);
  } else if (o < 512) {
    int d = o - 256;
    float v = by[d];
    #pragma unroll
    for (int t = 0; t < 3; t++) {
      int ll = l + t - 1;
      if (ll >= 0 && ll < SEQ) v += xyz[(brow + ll) * 768 + o] * wy[d * 3 + t];
    }
    yc[ml * 256 + d] = silu_f(v);
  } else {
    int d = o - 512;
    float v = bz[d];
    #pragma unroll
    for (int t = 0; t < 5; t++) {
      int ll = l + t - 2;
      if (ll >= 0 && ll < SEQ) v += xyz[(brow + ll) * 768 + o] * wz[d * 5 + t];
    }
    zc[ml * 256 + d] = silu_f(v);
  }
}

// ---------------------------------------------------------------------------
// Chunked selective scan. dtv holds precomputed delta.
// ---------------------------------------------------------------------------
template<bool PASSC>
__global__ __launch_bounds__(256)
void scan_k(const float* __restrict__ xc,     // u, (MT,256)
            const float* __restrict__ dtv,    // delta, (MT,256)
            const float* __restrict__ xdbl,   // (MT,48): [dt_r | B | C]
            const float* __restrict__ A_log,
            const float* __restrict__ Dp,
            const float* __restrict__ Hstart,
            float* __restrict__ Pbuf, float* __restrict__ hfbuf,
            float* __restrict__ pout)
{
  __shared__ float dt_s[LC][16], du_s[LC][16], Bc_s[LC][16];
  __shared__ float u_s[LC][16], Cc_s[LC][16];
  __shared__ float y_s[16][LC + 1];
  const int tid = threadIdx.x;
  const int n = tid & 15, dl = tid >> 4;
  const int ch = blockIdx.x;
  const int d0 = blockIdx.y * 16;
  const int b  = blockIdx.z;
  const int d  = d0 + dl;
  const int t0 = ch * LC;
  const size_t brow = (size_t)b * SEQ;

  #pragma unroll
  for (int i = 0; i < 4; i++) {
    int idx = tid + i * 256;
    int t = idx >> 4, dd = idx & 15;
    size_t row = brow + t0 + t;
    float uval = xc [row * 256 + d0 + dd];
    float dval = dtv[row * 256 + d0 + dd];
    dt_s[t][dd] = dval;
    du_s[t][dd] = dval * uval;
    Bc_s[t][dd] = xdbl[row * 48 + 16 + dd];
    if constexpr (PASSC) {
      u_s [t][dd] = uval;
      Cc_s[t][dd] = xdbl[row * 48 + 32 + dd];
    }
  }
  __syncthreads();

  const float A_dn = -__expf(A_log[d * NST + n]);
  const float Dd = Dp[d];
  const size_t cidx = (((size_t)b * DM + d) * NST + n) * NCHK + ch;

  float h = PASSC ? Hstart[cidx] : 0.f;
  float P = 1.f;
  #pragma unroll 4
  for (int t = 0; t < LC; t++) {
    float delta = dt_s[t][dl];
    float dA = __expf(delta * A_dn);
    float dBu = du_s[t][dl] * Bc_s[t][n];
    h = fmaf(dA, h, dBu);
    if constexpr (!PASSC) {
      P *= dA;
    } else {
      float yv = h * Cc_s[t][n];
      #pragma unroll
      for (int off = 1; off < 16; off <<= 1) yv += __shfl_xor(yv, off);
      if (n == 0) y_s[dl][t] = fmaf(Dd, u_s[t][dl], yv);
    }
  }

  if constexpr (!PASSC) {
    Pbuf[cidx] = P;
    hfbuf[cidx] = h;
  } else {
    __syncthreads();
    #pragma unroll
    for (int i = 0; i < 4; i++) {
      int idx = tid + i * 256;
      int t = idx >> 4, dd = idx & 15;
      pout[(brow + t0 + t) * 256 + d0 + dd] = y_s[dd][t];
    }
  }
}

__global__ __launch_bounds__(256)
void scan_mid_k(const float* __restrict__ Pbuf, const float* __restrict__ hfbuf,
                float* __restrict__ Hstart)
{
  int tid = blockIdx.x * 256 + threadIdx.x;   // 0..16383
  size_t base = (size_t)tid * NCHK;
  float H = 0.f;
  for (int c = 0; c < NCHK; c++) {
    Hstart[base + c] = H;
    H = Pbuf[base + c] * H + hfbuf[base + c];
  }
}

// ---------------------------------------------------------------------------
extern "C" void kernel_launch(void* const* d_in, const int* in_sizes, int n_in,
                              void* d_out, int out_size, void* d_ws, size_t ws_size,
                              hipStream_t stream)
{
  const float* hs    = (const float*)d_in[0];
  const float* w_in  = (const float*)d_in[1];
  const float* w_xp  = (const float*)d_in[2];
  const float* w_dt  = (const float*)d_in[3];
  const float* b_dt  = (const float*)d_in[4];
  const float* A_log = (const float*)d_in[5];
  const float* Dp    = (const float*)d_in[6];
  const float* w_o1  = (const float*)d_in[7];
  const float* cwx   = (const float*)d_in[8];
  const float* cbx   = (const float*)d_in[9];
  const float* cwy   = (const float*)d_in[10];
  const float* cby   = (const float*)d_in[11];
  const float* cwz   = (const float*)d_in[12];
  const float* cbz   = (const float*)d_in[13];

  float* ws = (float*)d_ws;
  float* xyz  = ws;                                   // MT*768
  float* xc   = ws  + (size_t)MT * 768;               // MT*256
  float* yc   = xc  + (size_t)MT * 256;               // MT*256
  float* zc   = yc  + (size_t)MT * 256;               // MT*256
  // reuse of region A (xyz dead after conv):
  float* xdbl = ws;                                   // MT*48
  float* dtv  = xdbl + (size_t)MT * 48;               // MT*256 (delta)
  float* pbuf = dtv  + (size_t)MT * 256;              // MT*256
  float* Pb   = pbuf + (size_t)MT * 256;
  float* hf   = Pb   + (size_t)B_SZ * DM * NST * NCHK;
  float* Hs   = hf   + (size_t)B_SZ * DM * NST * NCHK;

  dim3 blk(256);

  // K1: xyz[M,768] = hs @ in_proj_w^T      (bf16 MFMA)
  mfma_gemm_k<0, false><<<dim3(768 / 128, MT / 128), blk, 0, stream>>>(
      hs, nullptr, w_in, xyz, 768, 256, nullptr, nullptr, nullptr);

  // K2: depthwise conv + SiLU -> xc, yc, zc  (b,l,d)
  conv_silu_k<<<dim3((MT * 768) / 256), blk, 0, stream>>>(
      xyz, cwx, cbx, cwy, cby, cwz, cbz, xc, yc, zc);

  // K3: x_dbl[M,48] = xc @ x_proj_w^T
  gemm_k<0><<<dim3(1, MT / 64), blk, 0, stream>>>(
      xc, w_xp, xdbl, MT, 48, 256, 256, nullptr);

  // K4: dtv[M,256] = softplus(x_dbl[:, :16] @ dt_proj_w^T + 2*dt_proj_b)
  gemm_k<3><<<dim3(256 / 64, MT / 64), blk, 0, stream>>>(
      xdbl, w_dt, dtv, MT, 256, 16, 48, b_dt);

  // K5-7: chunked selective scan -> pbuf (b,l,d)
  scan_k<false><<<dim3(NCHK, DM / 16, B_SZ), blk, 0, stream>>>(
      xc, dtv, xdbl, A_log, Dp, nullptr, Pb, hf, nullptr);
  scan_mid_k<<<dim3((B_SZ * DM * NST) / 256), blk, 0, stream>>>(Pb, hf, Hs);
  scan_k<true><<<dim3(NCHK, DM / 16, B_SZ), blk, 0, stream>>>(
      xc, dtv, xdbl, A_log, Dp, Hs, nullptr, nullptr, pbuf);

  // K8: out = ((pbuf*yc) @ out_proj1_w^T) * zc * cwx + cbx   (bf16 MFMA)
  mfma_gemm_k<2, true><<<dim3(256 / 128, MT / 128), blk, 0, stream>>>(
      pbuf, yc, w_o1, (float*)d_out, 256, 256, cbx, zc, cwx);
}

// Round 6
// 304.121 us; speedup vs baseline: 2.4364x; 1.0099x over previous
//
#include <hip/hip_runtime.h>
#include <hip/hip_bf16.h>
#include <math.h>

typedef __hip_bfloat16 bf16;
typedef __attribute__((ext_vector_type(8))) short bf16x8;
typedef __attribute__((ext_vector_type(4))) float f32x4;

#define B_SZ 4
#define SEQ  4096
#define DM   256
#define NST  16
#define NCHK 64
#define LC   (SEQ/NCHK)      /* 64 */
#define MT   (B_SZ*SEQ)      /* 16384 rows of (b,l) */

__device__ __forceinline__ float silu_f(float v){ return v / (1.f + __expf(-v)); }
__device__ __forceinline__ float softplus_f(float v){
  return (v > 15.f) ? v : __logf(1.f + __expf(v));
}
__device__ __forceinline__ short f2bf(float f){
  union { bf16 h; short s; } u; u.h = __float2bfloat16(f); return u.s;
}

// ---------------------------------------------------------------------------
// MFMA bf16 GEMM: Out[M,N] = (A[M,K] (* A2 elementwise)) @ Bw[N,K]^T, fp32 in/out.
// Block 256 thr = 4 waves (2x2), tile 128x128, BK=32. A/B staged fp32->bf16.
// EPI 0: plain fp32 store. EPI 2: (acc * zc[m,n] * cwx[n] + bias[n]).
// ---------------------------------------------------------------------------
template<int EPI, bool A2M>
__global__ __launch_bounds__(256)
void mfma_gemm_k(const float* __restrict__ A, const float* __restrict__ A2,
                 const float* __restrict__ Bw, float* __restrict__ Out,
                 int N, int K,
                 const float* __restrict__ bias, const float* __restrict__ zc,
                 const float* __restrict__ cwx)
{
  constexpr int BM = 128, BN = 128, BK = 32, LDP = 40;  // pad 32->40 shorts
  __shared__ short As[BM * LDP];
  __shared__ short Bs[BN * LDP];
  const int tid  = threadIdx.x;
  const int wave = tid >> 6, lane = tid & 63;
  const int quad = lane >> 4, l16 = lane & 15;
  const int wm = (wave & 1) * 64, wn = (wave >> 1) * 64;
  const int m0 = blockIdx.y * BM, n0 = blockIdx.x * BN;
  const int srow = tid >> 3;            // 0..31 (row within 32-row pass)
  const int skq  = (tid & 7) * 4;       // k offset 0,4,..,28

  f32x4 acc[4][4] = {};

  for (int k0 = 0; k0 < K; k0 += BK) {
    #pragma unroll
    for (int p = 0; p < 4; p++) {
      int row = p * 32 + srow;
      size_t ga = (size_t)(m0 + row) * K + k0 + skq;
      float4 q = *(const float4*)(A + ga);
      if constexpr (A2M) {
        float4 r = *(const float4*)(A2 + ga);
        q.x *= r.x; q.y *= r.y; q.z *= r.z; q.w *= r.w;
      }
      short4 s; s.x = f2bf(q.x); s.y = f2bf(q.y); s.z = f2bf(q.z); s.w = f2bf(q.w);
      *(short4*)&As[row * LDP + skq] = s;
      size_t gb = (size_t)(n0 + row) * K + k0 + skq;
      float4 qb = *(const float4*)(Bw + gb);
      short4 sb; sb.x = f2bf(qb.x); sb.y = f2bf(qb.y); sb.z = f2bf(qb.z); sb.w = f2bf(qb.w);
      *(short4*)&Bs[row * LDP + skq] = sb;
    }
    __syncthreads();
    bf16x8 fa[4], fb[4];
    #pragma unroll
    for (int i = 0; i < 4; i++) {
      fa[i] = *(const bf16x8*)&As[(wm + i * 16 + l16) * LDP + quad * 8];
      fb[i] = *(const bf16x8*)&Bs[(wn + i * 16 + l16) * LDP + quad * 8];
    }
    #pragma unroll
    for (int i = 0; i < 4; i++)
      #pragma unroll
      for (int j = 0; j < 4; j++)
        acc[i][j] = __builtin_amdgcn_mfma_f32_16x16x32_bf16(fa[i], fb[j], acc[i][j], 0, 0, 0);
    __syncthreads();
  }

  #pragma unroll
  for (int i = 0; i < 4; i++) {
    #pragma unroll
    for (int j = 0; j < 4; j++) {
      int n = n0 + wn + j * 16 + l16;
      #pragma unroll
      for (int r = 0; r < 4; r++) {
        int m = m0 + wm + i * 16 + quad * 4 + r;
        float v = acc[i][j][r];
        if constexpr (EPI == 2)
          v = v * zc[(size_t)m * N + n] * cwx[n] + bias[n];
        Out[(size_t)m * N + n] = v;
      }
    }
  }
}

// ---------------------------------------------------------------------------
// Vector-fp32 tiled GEMM (small shapes K3/K4).
// EPI 0: store fp32. EPI 3: fp32 store of softplus(acc + 2*bias[n]).
// ---------------------------------------------------------------------------
template<int EPI>
__global__ __launch_bounds__(256)
void gemm_k(const float* __restrict__ A,
            const float* __restrict__ Bw, void* __restrict__ Out,
            int M, int N, int K, int lda,
            const float* __restrict__ bias)
{
  constexpr int TM = 64, TN = 64, TK = 16;
  __shared__ __align__(16) float As[TK][TM + 4];
  __shared__ __align__(16) float Bs[TK][TN + 4];
  const int tid = threadIdx.x;
  const int tn = tid & 15, tm = tid >> 4;
  const int n0 = blockIdx.x * TN, m0 = blockIdx.y * TM;
  float acc[4][4] = {};
  const int ml = tid >> 2;          // 0..63
  const int kq = (tid & 3) << 2;    // 0,4,8,12

  for (int k0 = 0; k0 < K; k0 += TK) {
    {
      size_t off = (size_t)(m0 + ml) * lda + k0 + kq;
      float4 q = *(const float4*)(A + off);
      As[kq+0][ml] = q.x; As[kq+1][ml] = q.y; As[kq+2][ml] = q.z; As[kq+3][ml] = q.w;
    }
    {
      float v0 = 0.f, v1 = 0.f, v2 = 0.f, v3 = 0.f;
      if (n0 + ml < N) {
        float4 q = *(const float4*)(Bw + (size_t)(n0 + ml) * K + k0 + kq);
        v0 = q.x; v1 = q.y; v2 = q.z; v3 = q.w;
      }
      Bs[kq+0][ml] = v0; Bs[kq+1][ml] = v1; Bs[kq+2][ml] = v2; Bs[kq+3][ml] = v3;
    }
    __syncthreads();
    #pragma unroll
    for (int k = 0; k < TK; k++) {
      float4 av = *(const float4*)&As[k][tm << 2];
      float4 bv = *(const float4*)&Bs[k][tn << 2];
      float a[4] = {av.x, av.y, av.z, av.w};
      float b[4] = {bv.x, bv.y, bv.z, bv.w};
      #pragma unroll
      for (int i = 0; i < 4; i++)
        #pragma unroll
        for (int j = 0; j < 4; j++)
          acc[i][j] = fmaf(a[i], b[j], acc[i][j]);
    }
    __syncthreads();
  }

  #pragma unroll
  for (int i = 0; i < 4; i++) {
    int m = m0 + (tm << 2) + i;
    #pragma unroll
    for (int j = 0; j < 4; j++) {
      int n = n0 + (tn << 2) + j;
      if (n < N) {
        float v = acc[i][j];
        if constexpr (EPI == 0) {
          ((float*)Out)[(size_t)m * N + n] = v;
        } else {
          ((float*)Out)[(size_t)m * N + n] = softplus_f(v + 2.f * bias[n]);
        }
      }
    }
  }
}

// ---------------------------------------------------------------------------
// Depthwise conv (k=1 / k=3 / k=5, 'same', cross-correlation) + SiLU.
// ---------------------------------------------------------------------------
__global__ __launch_bounds__(256)
void conv_silu_k(const float* __restrict__ xyz,
                 const float* __restrict__ wx, const float* __restrict__ bx,
                 const float* __restrict__ wy, const float* __restrict__ by,
                 const float* __restrict__ wz, const float* __restrict__ bz,
                 float* __restrict__ xc, float* __restrict__ yc,
                 float* __restrict__ zc)
{
  size_t idx = (size_t)blockIdx.x * 256 + threadIdx.x;   // over MT*768
  int o = (int)(idx % 768);
  size_t ml = idx / 768;                 // b*SEQ + l
  int l = (int)(ml % SEQ);
  size_t brow = ml - (size_t)l;          // b*SEQ
  if (o < 256) {
    float v = xyz[idx] * wx[o] + bx[o];
    xc[ml * 256 + o] = silu_f(v);
  } else if (o < 512) {
    int d = o - 256;
    float v = by[d];
    #pragma unroll
    for (int t = 0; t < 3; t++) {
      int ll = l + t - 1;
      if (ll >= 0 && ll < SEQ) v += xyz[(brow + ll) * 768 + o] * wy[d * 3 + t];
    }
    yc[ml * 256 + d] = silu_f(v);
  } else {
    int d = o - 512;
    float v = bz[d];
    #pragma unroll
    for (int t = 0; t < 5; t++) {
      int ll = l + t - 2;
      if (ll >= 0 && ll < SEQ) v += xyz[(brow + ll) * 768 + o] * wz[d * 5 + t];
    }
    zc[ml * 256 + d] = silu_f(v);
  }
}

// ---------------------------------------------------------------------------
// Chunked selective scan, t-unrolled x4 with interleaved shfl reductions.
// Thread = (dl, n). Pass A: chunk-local final state + decay product.
// Pass C: start from Hstart, emit y (+ D*u folded in via y_s staging init).
// LDS: pass A = 12 KB; pass C = 20 KB exactly (8 blocks/CU both).
// ---------------------------------------------------------------------------
template<bool PASSC>
__global__ __launch_bounds__(256)
void scan_k(const float* __restrict__ xc,     // u, (MT,256)
            const float* __restrict__ dtv,    // delta, (MT,256)
            const float* __restrict__ xdbl,   // (MT,48): [dt_r | B | C]
            const float* __restrict__ A_log,
            const float* __restrict__ Dp,
            const float* __restrict__ Hstart,
            float* __restrict__ Pbuf, float* __restrict__ hfbuf,
            float* __restrict__ pout)
{
  __shared__ float dt_s[LC * 16], du_s[LC * 16], Bc_s[LC * 16];
  __shared__ float Cc_s[PASSC ? LC * 16 : 16];
  __shared__ float y_s [PASSC ? LC * 16 : 16];   // y_s[t*16+dl], transposed
  const int tid = threadIdx.x;
  const int n = tid & 15, dl = tid >> 4;
  const int ch = blockIdx.x;
  const int d0 = blockIdx.y * 16;
  const int b  = blockIdx.z;
  const int d  = d0 + dl;
  const int t0 = ch * LC;
  const size_t brow = (size_t)b * SEQ;

  const float Dval = PASSC ? Dp[d0 + n] : 0.f;
  #pragma unroll
  for (int i = 0; i < 4; i++) {               // cooperative coalesced staging
    int t = (tid >> 4) + i * 16;              // row within chunk
    size_t row = brow + t0 + t;
    float uval = xc [row * 256 + d0 + n];
    float dval = dtv[row * 256 + d0 + n];
    dt_s[t * 16 + n] = dval;
    du_s[t * 16 + n] = dval * uval;
    Bc_s[t * 16 + n] = xdbl[row * 48 + 16 + n];
    if constexpr (PASSC) {
      Cc_s[t * 16 + n] = xdbl[row * 48 + 32 + n];
      y_s [t * 16 + n] = Dval * uval;         // pre-fold D*u
    }
  }
  __syncthreads();

  const float A_dn = -__expf(A_log[d * NST + n]);
  const size_t cidx = (((size_t)b * DM + d) * NST + n) * NCHK + ch;

  float h = PASSC ? Hstart[cidx] : 0.f;
  float P = 1.f;
  for (int t4 = 0; t4 < LC; t4 += 4) {
    float dA[4], dBu[4];
    #pragma unroll
    for (int j = 0; j < 4; j++) {             // independent: pipelined exps
      float delta = dt_s[(t4 + j) * 16 + dl];
      dA[j]  = __expf(delta * A_dn);
      dBu[j] = du_s[(t4 + j) * 16 + dl] * Bc_s[(t4 + j) * 16 + n];
    }
    if constexpr (!PASSC) {
      #pragma unroll
      for (int j = 0; j < 4; j++) {
        h = fmaf(dA[j], h, dBu[j]);
        P *= dA[j];
      }
    } else {
      float yv[4];
      #pragma unroll
      for (int j = 0; j < 4; j++) {
        h = fmaf(dA[j], h, dBu[j]);
        yv[j] = h * Cc_s[(t4 + j) * 16 + n];
      }
      #pragma unroll
      for (int off = 1; off < 16; off <<= 1) {   // 4 interleaved chains
        #pragma unroll
        for (int j = 0; j < 4; j++) yv[j] += __shfl_xor(yv[j], off);
      }
      if (n == 0) {
        #pragma unroll
        for (int j = 0; j < 4; j++) y_s[(t4 + j) * 16 + dl] += yv[j];
      }
    }
  }

  if constexpr (!PASSC) {
    Pbuf[cidx] = P;
    hfbuf[cidx] = h;
  } else {
    __syncthreads();
    #pragma unroll
    for (int i = 0; i < 4; i++) {             // coalesced writeback
      int t = (tid >> 4) + i * 16;
      pout[(brow + t0 + t) * 256 + d0 + n] = y_s[t * 16 + n];
    }
  }
}

// serial combine across the 64 chunks; one thread per (b,d,n) chain
__global__ __launch_bounds__(256)
void scan_mid_k(const float* __restrict__ Pbuf, const float* __restrict__ hfbuf,
                float* __restrict__ Hstart)
{
  int tid = blockIdx.x * 256 + threadIdx.x;   // 0..16383
  size_t base = (size_t)tid * NCHK;
  float H = 0.f;
  for (int c = 0; c < NCHK; c++) {
    Hstart[base + c] = H;
    H = Pbuf[base + c] * H + hfbuf[base + c];
  }
}

// ---------------------------------------------------------------------------
extern "C" void kernel_launch(void* const* d_in, const int* in_sizes, int n_in,
                              void* d_out, int out_size, void* d_ws, size_t ws_size,
                              hipStream_t stream)
{
  const float* hs    = (const float*)d_in[0];
  const float* w_in  = (const float*)d_in[1];
  const float* w_xp  = (const float*)d_in[2];
  const float* w_dt  = (const float*)d_in[3];
  const float* b_dt  = (const float*)d_in[4];
  const float* A_log = (const float*)d_in[5];
  const float* Dp    = (const float*)d_in[6];
  const float* w_o1  = (const float*)d_in[7];
  const float* cwx   = (const float*)d_in[8];
  const float* cbx   = (const float*)d_in[9];
  const float* cwy   = (const float*)d_in[10];
  const float* cby   = (const float*)d_in[11];
  const float* cwz   = (const float*)d_in[12];
  const float* cbz   = (const float*)d_in[13];

  float* ws = (float*)d_ws;
  float* xyz  = ws;                                   // MT*768
  float* xc   = ws  + (size_t)MT * 768;               // MT*256
  float* yc   = xc  + (size_t)MT * 256;               // MT*256
  float* zc   = yc  + (size_t)MT * 256;               // MT*256
  // reuse of region A (xyz dead after conv):
  float* xdbl = ws;                                   // MT*48
  float* dtv  = xdbl + (size_t)MT * 48;               // MT*256 (delta)
  float* pbuf = dtv  + (size_t)MT * 256;              // MT*256
  float* Pb   = pbuf + (size_t)MT * 256;
  float* hf   = Pb   + (size_t)B_SZ * DM * NST * NCHK;
  float* Hs   = hf   + (size_t)B_SZ * DM * NST * NCHK;

  dim3 blk(256);

  // K1: xyz[M,768] = hs @ in_proj_w^T      (bf16 MFMA)
  mfma_gemm_k<0, false><<<dim3(768 / 128, MT / 128), blk, 0, stream>>>(
      hs, nullptr, w_in, xyz, 768, 256, nullptr, nullptr, nullptr);

  // K2: depthwise conv + SiLU -> xc, yc, zc  (b,l,d)
  conv_silu_k<<<dim3((MT * 768) / 256), blk, 0, stream>>>(
      xyz, cwx, cbx, cwy, cby, cwz, cbz, xc, yc, zc);

  // K3: x_dbl[M,48] = xc @ x_proj_w^T
  gemm_k<0><<<dim3(1, MT / 64), blk, 0, stream>>>(
      xc, w_xp, xdbl, MT, 48, 256, 256, nullptr);

  // K4: dtv[M,256] = softplus(x_dbl[:, :16] @ dt_proj_w^T + 2*dt_proj_b)
  gemm_k<3><<<dim3(256 / 64, MT / 64), blk, 0, stream>>>(
      xdbl, w_dt, dtv, MT, 256, 16, 48, b_dt);

  // K5-7: chunked selective scan -> pbuf (b,l,d)
  scan_k<false><<<dim3(NCHK, DM / 16, B_SZ), blk, 0, stream>>>(
      xc, dtv, xdbl, A_log, Dp, nullptr, Pb, hf, nullptr);
  scan_mid_k<<<dim3((B_SZ * DM * NST) / 256), blk, 0, stream>>>(Pb, hf, Hs);
  scan_k<true><<<dim3(NCHK, DM / 16, B_SZ), blk, 0, stream>>>(
      xc, dtv, xdbl, A_log, Dp, Hs, nullptr, nullptr, pbuf);

  // K8: out = ((pbuf*yc) @ out_proj1_w^T) * zc * cwx + cbx   (bf16 MFMA)
  mfma_gemm_k<2, true><<<dim3(256 / 128, MT / 128), blk, 0, stream>>>(
      pbuf, yc, w_o1, (float*)d_out, 256, 256, cbx, zc, cwx);
}

// Round 8
// 262.054 us; speedup vs baseline: 2.8276x; 1.1605x over previous
//
#include <hip/hip_runtime.h>
#include <hip/hip_bf16.h>
#include <math.h>

typedef __hip_bfloat16 bf16;
typedef __attribute__((ext_vector_type(8))) short bf16x8;
typedef __attribute__((ext_vector_type(4))) float f32x4;

#define B_SZ 4
#define SEQ  4096
#define DM   256
#define NST  16
#define NCHK 64
#define LC   (SEQ/NCHK)      /* 64 */
#define MT   (B_SZ*SEQ)      /* 16384 rows of (b,l) */

__device__ __forceinline__ float silu_f(float v){ return v / (1.f + __expf(-v)); }
__device__ __forceinline__ float softplus_f(float v){
  return (v > 15.f) ? v : __logf(1.f + __expf(v));
}
__device__ __forceinline__ short f2bf(float f){
  union { bf16 h; short s; } u; u.h = __float2bfloat16(f); return u.s;
}

// DPP row_shr:N add step: lane i += lane(i-N) within its 16-lane row
// (invalid sources read 0). After N=8,4,2,1 the LAST lane (15) of each
// row holds the full 16-lane sum.
template<int CTRL>
__device__ __forceinline__ float dpp_add_step(float v){
  int x = __builtin_amdgcn_update_dpp(0, __float_as_int(v), CTRL, 0xf, 0xf, true);
  return v + __int_as_float(x);
}

// ---------------------------------------------------------------------------
// MFMA bf16 GEMM: Out[M,N] = (A[M,K] (* A2 elementwise)) @ Bw[N,K]^T, fp32 in/out.
// Block 256 thr = 4 waves (2x2), tile 128x128, BK=32. A/B staged fp32->bf16.
// EPI 0: plain fp32 store. EPI 2: (acc * zc[m,n] * cwx[n] + bias[n]).
// ---------------------------------------------------------------------------
template<int EPI, bool A2M>
__global__ __launch_bounds__(256)
void mfma_gemm_k(const float* __restrict__ A, const float* __restrict__ A2,
                 const float* __restrict__ Bw, float* __restrict__ Out,
                 int N, int K,
                 const float* __restrict__ bias, const float* __restrict__ zc,
                 const float* __restrict__ cwx)
{
  constexpr int BM = 128, BN = 128, BK = 32, LDP = 40;  // pad 32->40 shorts
  __shared__ short As[BM * LDP];
  __shared__ short Bs[BN * LDP];
  const int tid  = threadIdx.x;
  const int wave = tid >> 6, lane = tid & 63;
  const int quad = lane >> 4, l16 = lane & 15;
  const int wm = (wave & 1) * 64, wn = (wave >> 1) * 64;
  const int m0 = blockIdx.y * BM, n0 = blockIdx.x * BN;
  const int srow = tid >> 3;            // 0..31 (row within 32-row pass)
  const int skq  = (tid & 7) * 4;       // k offset 0,4,..,28

  f32x4 acc[4][4] = {};

  for (int k0 = 0; k0 < K; k0 += BK) {
    #pragma unroll
    for (int p = 0; p < 4; p++) {
      int row = p * 32 + srow;
      size_t ga = (size_t)(m0 + row) * K + k0 + skq;
      float4 q = *(const float4*)(A + ga);
      if constexpr (A2M) {
        float4 r = *(const float4*)(A2 + ga);
        q.x *= r.x; q.y *= r.y; q.z *= r.z; q.w *= r.w;
      }
      short4 s; s.x = f2bf(q.x); s.y = f2bf(q.y); s.z = f2bf(q.z); s.w = f2bf(q.w);
      *(short4*)&As[row * LDP + skq] = s;
      size_t gb = (size_t)(n0 + row) * K + k0 + skq;
      float4 qb = *(const float4*)(Bw + gb);
      short4 sb; sb.x = f2bf(qb.x); sb.y = f2bf(qb.y); sb.z = f2bf(qb.z); sb.w = f2bf(qb.w);
      *(short4*)&Bs[row * LDP + skq] = sb;
    }
    __syncthreads();
    bf16x8 fa[4], fb[4];
    #pragma unroll
    for (int i = 0; i < 4; i++) {
      fa[i] = *(const bf16x8*)&As[(wm + i * 16 + l16) * LDP + quad * 8];
      fb[i] = *(const bf16x8*)&Bs[(wn + i * 16 + l16) * LDP + quad * 8];
    }
    #pragma unroll
    for (int i = 0; i < 4; i++)
      #pragma unroll
      for (int j = 0; j < 4; j++)
        acc[i][j] = __builtin_amdgcn_mfma_f32_16x16x32_bf16(fa[i], fb[j], acc[i][j], 0, 0, 0);
    __syncthreads();
  }

  #pragma unroll
  for (int i = 0; i < 4; i++) {
    #pragma unroll
    for (int j = 0; j < 4; j++) {
      int n = n0 + wn + j * 16 + l16;
      #pragma unroll
      for (int r = 0; r < 4; r++) {
        int m = m0 + wm + i * 16 + quad * 4 + r;
        float v = acc[i][j][r];
        if constexpr (EPI == 2)
          v = v * zc[(size_t)m * N + n] * cwx[n] + bias[n];
        Out[(size_t)m * N + n] = v;
      }
    }
  }
}

// ---------------------------------------------------------------------------
// Vector-fp32 tiled GEMM (small shapes K3/K4).
// EPI 0: store fp32. EPI 3: fp32 store of softplus(acc + 2*bias[n]).
// ---------------------------------------------------------------------------
template<int EPI>
__global__ __launch_bounds__(256)
void gemm_k(const float* __restrict__ A,
            const float* __restrict__ Bw, void* __restrict__ Out,
            int M, int N, int K, int lda,
            const float* __restrict__ bias)
{
  constexpr int TM = 64, TN = 64, TK = 16;
  __shared__ __align__(16) float As[TK][TM + 4];
  __shared__ __align__(16) float Bs[TK][TN + 4];
  const int tid = threadIdx.x;
  const int tn = tid & 15, tm = tid >> 4;
  const int n0 = blockIdx.x * TN, m0 = blockIdx.y * TM;
  float acc[4][4] = {};
  const int ml = tid >> 2;          // 0..63
  const int kq = (tid & 3) << 2;    // 0,4,8,12

  for (int k0 = 0; k0 < K; k0 += TK) {
    {
      size_t off = (size_t)(m0 + ml) * lda + k0 + kq;
      float4 q = *(const float4*)(A + off);
      As[kq+0][ml] = q.x; As[kq+1][ml] = q.y; As[kq+2][ml] = q.z; As[kq+3][ml] = q.w;
    }
    {
      float v0 = 0.f, v1 = 0.f, v2 = 0.f, v3 = 0.f;
      if (n0 + ml < N) {
        float4 q = *(const float4*)(Bw + (size_t)(n0 + ml) * K + k0 + kq);
        v0 = q.x; v1 = q.y; v2 = q.z; v3 = q.w;
      }
      Bs[kq+0][ml] = v0; Bs[kq+1][ml] = v1; Bs[kq+2][ml] = v2; Bs[kq+3][ml] = v3;
    }
    __syncthreads();
    #pragma unroll
    for (int k = 0; k < TK; k++) {
      float4 av = *(const float4*)&As[k][tm << 2];
      float4 bv = *(const float4*)&Bs[k][tn << 2];
      float a[4] = {av.x, av.y, av.z, av.w};
      float b[4] = {bv.x, bv.y, bv.z, bv.w};
      #pragma unroll
      for (int i = 0; i < 4; i++)
        #pragma unroll
        for (int j = 0; j < 4; j++)
          acc[i][j] = fmaf(a[i], b[j], acc[i][j]);
    }
    __syncthreads();
  }

  #pragma unroll
  for (int i = 0; i < 4; i++) {
    int m = m0 + (tm << 2) + i;
    #pragma unroll
    for (int j = 0; j < 4; j++) {
      int n = n0 + (tn << 2) + j;
      if (n < N) {
        float v = acc[i][j];
        if constexpr (EPI == 0) {
          ((float*)Out)[(size_t)m * N + n] = v;
        } else {
          ((float*)Out)[(size_t)m * N + n] = softplus_f(v + 2.f * bias[n]);
        }
      }
    }
  }
}

// ---------------------------------------------------------------------------
// Depthwise conv (k=1 / k=3 / k=5, 'same', cross-correlation) + SiLU.
// ---------------------------------------------------------------------------
__global__ __launch_bounds__(256)
void conv_silu_k(const float* __restrict__ xyz,
                 const float* __restrict__ wx, const float* __restrict__ bx,
                 const float* __restrict__ wy, const float* __restrict__ by,
                 const float* __restrict__ wz, const float* __restrict__ bz,
                 float* __restrict__ xc, float* __restrict__ yc,
                 float* __restrict__ zc)
{
  size_t idx = (size_t)blockIdx.x * 256 + threadIdx.x;   // over MT*768
  int o = (int)(idx % 768);
  size_t ml = idx / 768;                 // b*SEQ + l
  int l = (int)(ml % SEQ);
  size_t brow = ml - (size_t)l;          // b*SEQ
  if (o < 256) {
    float v = xyz[idx] * wx[o] + bx[o];
    xc[ml * 256 + o] = silu_f(v);
  } else if (o < 512) {
    int d = o - 256;
    float v = by[d];
    #pragma unroll
    for (int t = 0; t < 3; t++) {
      int ll = l + t - 1;
      if (ll >= 0 && ll < SEQ) v += xyz[(brow + ll) * 768 + o] * wy[d * 3 + t];
    }
    yc[ml * 256 + d] = silu_f(v);
  } else {
    int d = o - 512;
    float v = bz[d];
    #pragma unroll
    for (int t = 0; t < 5; t++) {
      int ll = l + t - 2;
      if (ll >= 0 && ll < SEQ) v += xyz[(brow + ll) * 768 + o] * wz[d * 5 + t];
    }
    zc[ml * 256 + d] = silu_f(v);
  }
}

// ---------------------------------------------------------------------------
// Chunked selective scan, t-unrolled x4. LDS-op-minimized:
//  - {delta, delta*u} paired float2 (broadcast read across n-lanes)
//  - {B, C} paired float2 (conflict-free 32-word span)
//  - n-reduction on VALU via DPP row_shr (sum lands in lane n==15)
//  - y staged write-only as float4 per t4 (transposed, +1 pad); D*u folded
//    at writeback from registers.
// ---------------------------------------------------------------------------
template<bool PASSC>
__global__ __launch_bounds__(256)
void scan_k(const float* __restrict__ xc,     // u, (MT,256)
            const float* __restrict__ dtv,    // delta, (MT,256)
            const float* __restrict__ xdbl,   // (MT,48): [dt_r | B | C]
            const float* __restrict__ A_log,
            const float* __restrict__ Dp,
            const float* __restrict__ Hstart,
            float* __restrict__ Pbuf, float* __restrict__ hfbuf,
            float* __restrict__ pout)
{
  __shared__ float2 du2_s[LC * 16];                    // {delta, delta*u}[t][ch]
  __shared__ float2 BC_s [PASSC ? LC * 16 : 16];       // {B, C}[t][n]
  __shared__ float  Bc_s [PASSC ? 16 : LC * 16];       // B[t][n] (pass A)
  __shared__ float  y_s  [PASSC ? 16 * 65 : 16];       // y[ch][t], pad 65
  const int tid = threadIdx.x;
  const int n = tid & 15, dl = tid >> 4;
  const int ch = blockIdx.x;
  const int d0 = blockIdx.y * 16;
  const int b  = blockIdx.z;
  const int d  = d0 + dl;
  const int t0 = ch * LC;
  const size_t brow = (size_t)b * SEQ;

  float u_r[4];
  #pragma unroll
  for (int i = 0; i < 4; i++) {               // cooperative coalesced staging
    int t = (tid >> 4) + i * 16;              // row within chunk
    size_t row = brow + t0 + t;
    float uval = xc [row * 256 + d0 + n];
    float dval = dtv[row * 256 + d0 + n];
    du2_s[t * 16 + n] = make_float2(dval, dval * uval);
    if constexpr (PASSC) {
      BC_s[t * 16 + n] = make_float2(xdbl[row * 48 + 16 + n],
                                     xdbl[row * 48 + 32 + n]);
      u_r[i] = uval;
    } else {
      Bc_s[t * 16 + n] = xdbl[row * 48 + 16 + n];
    }
  }
  __syncthreads();

  const float A_dn = -__expf(A_log[d * NST + n]);
  const size_t cidx = (((size_t)b * DM + d) * NST + n) * NCHK + ch;

  float h = PASSC ? Hstart[cidx] : 0.f;
  float P = 1.f;
  for (int t4 = 0; t4 < LC; t4 += 4) {
    float dA[4], dBu[4];
    #pragma unroll
    for (int j = 0; j < 4; j++) {             // independent: pipelined exps
      float2 du = du2_s[(t4 + j) * 16 + dl];
      dA[j] = __expf(du.x * A_dn);
      if constexpr (PASSC) dBu[j] = du.y;     // * B below
      else                 dBu[j] = du.y * Bc_s[(t4 + j) * 16 + n];
    }
    if constexpr (!PASSC) {
      #pragma unroll
      for (int j = 0; j < 4; j++) {
        h = fmaf(dA[j], h, dBu[j]);
        P *= dA[j];
      }
    } else {
      float yv[4];
      #pragma unroll
      for (int j = 0; j < 4; j++) {
        float2 bc = BC_s[(t4 + j) * 16 + n];
        h = fmaf(dA[j], h, dBu[j] * bc.x);
        yv[j] = h * bc.y;
      }
      // 16-lane row reduction on VALU (DPP), 4 interleaved chains;
      // row_shr accumulates toward higher lanes -> sum in lane 15.
      #pragma unroll
      for (int j = 0; j < 4; j++) yv[j] = dpp_add_step<0x118>(yv[j]); // shr8
      #pragma unroll
      for (int j = 0; j < 4; j++) yv[j] = dpp_add_step<0x114>(yv[j]); // shr4
      #pragma unroll
      for (int j = 0; j < 4; j++) yv[j] = dpp_add_step<0x112>(yv[j]); // shr2
      #pragma unroll
      for (int j = 0; j < 4; j++) yv[j] = dpp_add_step<0x111>(yv[j]); // shr1
      if (n == 15)
        *(float4*)&y_s[dl * 65 + t4] = make_float4(yv[0], yv[1], yv[2], yv[3]);
    }
  }

  if constexpr (!PASSC) {
    Pbuf[cidx] = P;
    hfbuf[cidx] = h;
  } else {
    __syncthreads();
    const float Dval = Dp[d0 + n];
    #pragma unroll
    for (int i = 0; i < 4; i++) {             // coalesced writeback
      int t = (tid >> 4) + i * 16;
      pout[(brow + t0 + t) * 256 + d0 + n] = fmaf(Dval, u_r[i], y_s[n * 65 + t]);
    }
  }
}

// serial combine across the 64 chunks; one thread per (b,d,n) chain
__global__ __launch_bounds__(256)
void scan_mid_k(const float* __restrict__ Pbuf, const float* __restrict__ hfbuf,
                float* __restrict__ Hstart)
{
  int tid = blockIdx.x * 256 + threadIdx.x;   // 0..16383
  size_t base = (size_t)tid * NCHK;
  float H = 0.f;
  for (int c = 0; c < NCHK; c++) {
    Hstart[base + c] = H;
    H = Pbuf[base + c] * H + hfbuf[base + c];
  }
}

// ---------------------------------------------------------------------------
extern "C" void kernel_launch(void* const* d_in, const int* in_sizes, int n_in,
                              void* d_out, int out_size, void* d_ws, size_t ws_size,
                              hipStream_t stream)
{
  const float* hs    = (const float*)d_in[0];
  const float* w_in  = (const float*)d_in[1];
  const float* w_xp  = (const float*)d_in[2];
  const float* w_dt  = (const float*)d_in[3];
  const float* b_dt  = (const float*)d_in[4];
  const float* A_log = (const float*)d_in[5];
  const float* Dp    = (const float*)d_in[6];
  const float* w_o1  = (const float*)d_in[7];
  const float* cwx   = (const float*)d_in[8];
  const float* cbx   = (const float*)d_in[9];
  const float* cwy   = (const float*)d_in[10];
  const float* cby   = (const float*)d_in[11];
  const float* cwz   = (const float*)d_in[12];
  const float* cbz   = (const float*)d_in[13];

  float* ws = (float*)d_ws;
  float* xyz  = ws;                                   // MT*768
  float* xc   = ws  + (size_t)MT * 768;               // MT*256
  float* yc   = xc  + (size_t)MT * 256;               // MT*256
  float* zc   = yc  + (size_t)MT * 256;               // MT*256
  // reuse of region A (xyz dead after conv):
  float* xdbl = ws;                                   // MT*48
  float* dtv  = xdbl + (size_t)MT * 48;               // MT*256 (delta)
  float* pbuf = dtv  + (size_t)MT * 256;              // MT*256
  float* Pb   = pbuf + (size_t)MT * 256;
  float* hf   = Pb   + (size_t)B_SZ * DM * NST * NCHK;
  float* Hs   = hf   + (size_t)B_SZ * DM * NST * NCHK;

  dim3 blk(256);

  // K1: xyz[M,768] = hs @ in_proj_w^T      (bf16 MFMA)
  mfma_gemm_k<0, false><<<dim3(768 / 128, MT / 128), blk, 0, stream>>>(
      hs, nullptr, w_in, xyz, 768, 256, nullptr, nullptr, nullptr);

  // K2: depthwise conv + SiLU -> xc, yc, zc  (b,l,d)
  conv_silu_k<<<dim3((MT * 768) / 256), blk, 0, stream>>>(
      xyz, cwx, cbx, cwy, cby, cwz, cbz, xc, yc, zc);

  // K3: x_dbl[M,48] = xc @ x_proj_w^T
  gemm_k<0><<<dim3(1, MT / 64), blk, 0, stream>>>(
      xc, w_xp, xdbl, MT, 48, 256, 256, nullptr);

  // K4: dtv[M,256] = softplus(x_dbl[:, :16] @ dt_proj_w^T + 2*dt_proj_b)
  gemm_k<3><<<dim3(256 / 64, MT / 64), blk, 0, stream>>>(
      xdbl, w_dt, dtv, MT, 256, 16, 48, b_dt);

  // K5-7: chunked selective scan -> pbuf (b,l,d)
  scan_k<false><<<dim3(NCHK, DM / 16, B_SZ), blk, 0, stream>>>(
      xc, dtv, xdbl, A_log, Dp, nullptr, Pb, hf, nullptr);
  scan_mid_k<<<dim3((B_SZ * DM * NST) / 256), blk, 0, stream>>>(Pb, hf, Hs);
  scan_k<true><<<dim3(NCHK, DM / 16, B_SZ), blk, 0, stream>>>(
      xc, dtv, xdbl, A_log, Dp, Hs, nullptr, nullptr, pbuf);

  // K8: out = ((pbuf*yc) @ out_proj1_w^T) * zc * cwx + cbx   (bf16 MFMA)
  mfma_gemm_k<2, true><<<dim3(256 / 128, MT / 128), blk, 0, stream>>>(
      pbuf, yc, w_o1, (float*)d_out, 256, 256, cbx, zc, cwx);
}

// Round 9
// 239.689 us; speedup vs baseline: 3.0914x; 1.0933x over previous
//
#include <hip/hip_runtime.h>
#include <hip/hip_bf16.h>
#include <math.h>

typedef __hip_bfloat16 bf16;
typedef __attribute__((ext_vector_type(8))) short bf16x8;
typedef __attribute__((ext_vector_type(4))) float f32x4;

#define B_SZ 4
#define SEQ  4096
#define DM   256
#define NST  16
#define NCHK 64
#define LC   (SEQ/NCHK)      /* 64 */
#define MT   (B_SZ*SEQ)      /* 16384 rows of (b,l) */
#define CT   4               /* l-tile per conv thread */

__device__ __forceinline__ float silu_f(float v){ return v / (1.f + __expf(-v)); }
__device__ __forceinline__ float softplus_f(float v){
  return (v > 15.f) ? v : __logf(1.f + __expf(v));
}
__device__ __forceinline__ short f2bf(float f){
  union { bf16 h; short s; } u; u.h = __float2bfloat16(f); return u.s;
}

// DPP row_shr:N add step: lane i += lane(i-N) within its 16-lane row
// (invalid sources read 0). After N=8,4,2,1 the LAST lane (15) of each
// row holds the full 16-lane sum.
template<int CTRL>
__device__ __forceinline__ float dpp_add_step(float v){
  int x = __builtin_amdgcn_update_dpp(0, __float_as_int(v), CTRL, 0xf, 0xf, true);
  return v + __int_as_float(x);
}

// ---------------------------------------------------------------------------
// MFMA bf16 GEMM: Out[M,N] = (A[M,K] (* A2 elementwise)) @ Bw[N,K]^T, fp32 in/out.
// Block 256 thr = 4 waves (2x2), tile 128x128, BK=32. A/B staged fp32->bf16.
// EPI 0: plain fp32 store. EPI 2: (acc * zc[m,n] * cwx[n] + bias[n]).
// ---------------------------------------------------------------------------
template<int EPI, bool A2M>
__global__ __launch_bounds__(256)
void mfma_gemm_k(const float* __restrict__ A, const float* __restrict__ A2,
                 const float* __restrict__ Bw, float* __restrict__ Out,
                 int N, int K,
                 const float* __restrict__ bias, const float* __restrict__ zc,
                 const float* __restrict__ cwx)
{
  constexpr int BM = 128, BN = 128, BK = 32, LDP = 40;  // pad 32->40 shorts
  __shared__ short As[BM * LDP];
  __shared__ short Bs[BN * LDP];
  const int tid  = threadIdx.x;
  const int wave = tid >> 6, lane = tid & 63;
  const int quad = lane >> 4, l16 = lane & 15;
  const int wm = (wave & 1) * 64, wn = (wave >> 1) * 64;
  const int m0 = blockIdx.y * BM, n0 = blockIdx.x * BN;
  const int srow = tid >> 3;            // 0..31 (row within 32-row pass)
  const int skq  = (tid & 7) * 4;       // k offset 0,4,..,28

  f32x4 acc[4][4] = {};

  for (int k0 = 0; k0 < K; k0 += BK) {
    #pragma unroll
    for (int p = 0; p < 4; p++) {
      int row = p * 32 + srow;
      size_t ga = (size_t)(m0 + row) * K + k0 + skq;
      float4 q = *(const float4*)(A + ga);
      if constexpr (A2M) {
        float4 r = *(const float4*)(A2 + ga);
        q.x *= r.x; q.y *= r.y; q.z *= r.z; q.w *= r.w;
      }
      short4 s; s.x = f2bf(q.x); s.y = f2bf(q.y); s.z = f2bf(q.z); s.w = f2bf(q.w);
      *(short4*)&As[row * LDP + skq] = s;
      size_t gb = (size_t)(n0 + row) * K + k0 + skq;
      float4 qb = *(const float4*)(Bw + gb);
      short4 sb; sb.x = f2bf(qb.x); sb.y = f2bf(qb.y); sb.z = f2bf(qb.z); sb.w = f2bf(qb.w);
      *(short4*)&Bs[row * LDP + skq] = sb;
    }
    __syncthreads();
    bf16x8 fa[4], fb[4];
    #pragma unroll
    for (int i = 0; i < 4; i++) {
      fa[i] = *(const bf16x8*)&As[(wm + i * 16 + l16) * LDP + quad * 8];
      fb[i] = *(const bf16x8*)&Bs[(wn + i * 16 + l16) * LDP + quad * 8];
    }
    #pragma unroll
    for (int i = 0; i < 4; i++)
      #pragma unroll
      for (int j = 0; j < 4; j++)
        acc[i][j] = __builtin_amdgcn_mfma_f32_16x16x32_bf16(fa[i], fb[j], acc[i][j], 0, 0, 0);
    __syncthreads();
  }

  #pragma unroll
  for (int i = 0; i < 4; i++) {
    #pragma unroll
    for (int j = 0; j < 4; j++) {
      int n = n0 + wn + j * 16 + l16;
      #pragma unroll
      for (int r = 0; r < 4; r++) {
        int m = m0 + wm + i * 16 + quad * 4 + r;
        float v = acc[i][j][r];
        if constexpr (EPI == 2)
          v = v * zc[(size_t)m * N + n] * cwx[n] + bias[n];
        Out[(size_t)m * N + n] = v;
      }
    }
  }
}

// ---------------------------------------------------------------------------
// Vector-fp32 tiled GEMM (small shapes K3/K4).
// EPI 0: store fp32. EPI 3: fp32 store of softplus(acc + 2*bias[n]).
// ---------------------------------------------------------------------------
template<int EPI>
__global__ __launch_bounds__(256)
void gemm_k(const float* __restrict__ A,
            const float* __restrict__ Bw, void* __restrict__ Out,
            int M, int N, int K, int lda,
            const float* __restrict__ bias)
{
  constexpr int TM = 64, TN = 64, TK = 16;
  __shared__ __align__(16) float As[TK][TM + 4];
  __shared__ __align__(16) float Bs[TK][TN + 4];
  const int tid = threadIdx.x;
  const int tn = tid & 15, tm = tid >> 4;
  const int n0 = blockIdx.x * TN, m0 = blockIdx.y * TM;
  float acc[4][4] = {};
  const int ml = tid >> 2;          // 0..63
  const int kq = (tid & 3) << 2;    // 0,4,8,12

  for (int k0 = 0; k0 < K; k0 += TK) {
    {
      size_t off = (size_t)(m0 + ml) * lda + k0 + kq;
      float4 q = *(const float4*)(A + off);
      As[kq+0][ml] = q.x; As[kq+1][ml] = q.y; As[kq+2][ml] = q.z; As[kq+3][ml] = q.w;
    }
    {
      float v0 = 0.f, v1 = 0.f, v2 = 0.f, v3 = 0.f;
      if (n0 + ml < N) {
        float4 q = *(const float4*)(Bw + (size_t)(n0 + ml) * K + k0 + kq);
        v0 = q.x; v1 = q.y; v2 = q.z; v3 = q.w;
      }
      Bs[kq+0][ml] = v0; Bs[kq+1][ml] = v1; Bs[kq+2][ml] = v2; Bs[kq+3][ml] = v3;
    }
    __syncthreads();
    #pragma unroll
    for (int k = 0; k < TK; k++) {
      float4 av = *(const float4*)&As[k][tm << 2];
      float4 bv = *(const float4*)&Bs[k][tn << 2];
      float a[4] = {av.x, av.y, av.z, av.w};
      float b[4] = {bv.x, bv.y, bv.z, bv.w};
      #pragma unroll
      for (int i = 0; i < 4; i++)
        #pragma unroll
        for (int j = 0; j < 4; j++)
          acc[i][j] = fmaf(a[i], b[j], acc[i][j]);
    }
    __syncthreads();
  }

  #pragma unroll
  for (int i = 0; i < 4; i++) {
    int m = m0 + (tm << 2) + i;
    #pragma unroll
    for (int j = 0; j < 4; j++) {
      int n = n0 + (tn << 2) + j;
      if (n < N) {
        float v = acc[i][j];
        if constexpr (EPI == 0) {
          ((float*)Out)[(size_t)m * N + n] = v;
        } else {
          ((float*)Out)[(size_t)m * N + n] = softplus_f(v + 2.f * bias[n]);
        }
      }
    }
  }
}

// ---------------------------------------------------------------------------
// Depthwise conv + SiLU, register-sliding-window, float4 channel quads.
// Thread = (c4, l-tile of CT). idx = lt*192 + c4 so each 64-lane wave spans
// exactly one branch (x: c4<64, y: 64..127, z: 128..191) -> no divergence;
// loads/stores are 1KB contiguous per wave.
// ---------------------------------------------------------------------------
__global__ __launch_bounds__(256)
void conv_silu_k(const float4* __restrict__ xyz4,   // (MT, 192) float4
                 const float* __restrict__ wx, const float* __restrict__ bx,
                 const float* __restrict__ wy, const float* __restrict__ by,
                 const float* __restrict__ wz, const float* __restrict__ bz,
                 float4* __restrict__ xc4, float4* __restrict__ yc4,
                 float4* __restrict__ zc4)
{
  int idx = blockIdx.x * 256 + threadIdx.x;     // over (MT/CT)*192
  int c4 = idx % 192;
  int lt = idx / 192;
  int row0 = lt * CT;                            // global (b*SEQ + l) base
  int l0 = row0 & (SEQ - 1);                     // l within batch

  float4 win[CT + 4];
  #pragma unroll
  for (int i = 0; i < CT + 4; i++) {
    int l = l0 + i - 2;
    if (l >= 0 && l < SEQ)
      win[i] = xyz4[(size_t)(row0 + i - 2) * 192 + c4];
    else
      win[i] = make_float4(0.f, 0.f, 0.f, 0.f);
  }

  if (c4 < 64) {                                 // x: k=1 pointwise
    int d = c4 * 4;
    float4 w  = *(const float4*)&wx[d];
    float4 bb = *(const float4*)&bx[d];
    #pragma unroll
    for (int t = 0; t < CT; t++) {
      float4 v = win[t + 2], o;
      o.x = silu_f(fmaf(v.x, w.x, bb.x));
      o.y = silu_f(fmaf(v.y, w.y, bb.y));
      o.z = silu_f(fmaf(v.z, w.z, bb.z));
      o.w = silu_f(fmaf(v.w, w.w, bb.w));
      xc4[(size_t)(row0 + t) * 64 + c4] = o;
    }
  } else if (c4 < 128) {                         // y: k=3
    int d = (c4 - 64) * 4;
    float wq[4][3];
    #pragma unroll
    for (int q = 0; q < 4; q++)
      #pragma unroll
      for (int j = 0; j < 3; j++) wq[q][j] = wy[(d + q) * 3 + j];
    float4 bb = *(const float4*)&by[d];
    #pragma unroll
    for (int t = 0; t < CT; t++) {
      float a0 = bb.x, a1 = bb.y, a2 = bb.z, a3 = bb.w;
      #pragma unroll
      for (int j = 0; j < 3; j++) {
        float4 v = win[t + 1 + j];
        a0 = fmaf(v.x, wq[0][j], a0);
        a1 = fmaf(v.y, wq[1][j], a1);
        a2 = fmaf(v.z, wq[2][j], a2);
        a3 = fmaf(v.w, wq[3][j], a3);
      }
      float4 o; o.x = silu_f(a0); o.y = silu_f(a1); o.z = silu_f(a2); o.w = silu_f(a3);
      yc4[(size_t)(row0 + t) * 64 + (c4 - 64)] = o;
    }
  } else {                                       // z: k=5
    int d = (c4 - 128) * 4;
    float wq[4][5];
    #pragma unroll
    for (int q = 0; q < 4; q++)
      #pragma unroll
      for (int j = 0; j < 5; j++) wq[q][j] = wz[(d + q) * 5 + j];
    float4 bb = *(const float4*)&bz[d];
    #pragma unroll
    for (int t = 0; t < CT; t++) {
      float a0 = bb.x, a1 = bb.y, a2 = bb.z, a3 = bb.w;
      #pragma unroll
      for (int j = 0; j < 5; j++) {
        float4 v = win[t + j];
        a0 = fmaf(v.x, wq[0][j], a0);
        a1 = fmaf(v.y, wq[1][j], a1);
        a2 = fmaf(v.z, wq[2][j], a2);
        a3 = fmaf(v.w, wq[3][j], a3);
      }
      float4 o; o.x = silu_f(a0); o.y = silu_f(a1); o.z = silu_f(a2); o.w = silu_f(a3);
      zc4[(size_t)(row0 + t) * 64 + (c4 - 128)] = o;
    }
  }
}

// ---------------------------------------------------------------------------
// Chunked selective scan, t-unrolled x4. LDS-op-minimized (see R7 notes).
// ---------------------------------------------------------------------------
template<bool PASSC>
__global__ __launch_bounds__(256)
void scan_k(const float* __restrict__ xc,     // u, (MT,256)
            const float* __restrict__ dtv,    // delta, (MT,256)
            const float* __restrict__ xdbl,   // (MT,48): [dt_r | B | C]
            const float* __restrict__ A_log,
            const float* __restrict__ Dp,
            const float* __restrict__ Hstart,
            float* __restrict__ Pbuf, float* __restrict__ hfbuf,
            float* __restrict__ pout)
{
  __shared__ float2 du2_s[LC * 16];                    // {delta, delta*u}[t][ch]
  __shared__ float2 BC_s [PASSC ? LC * 16 : 16];       // {B, C}[t][n]
  __shared__ float  Bc_s [PASSC ? 16 : LC * 16];       // B[t][n] (pass A)
  __shared__ float  y_s  [PASSC ? 16 * 65 : 16];       // y[ch][t], pad 65
  const int tid = threadIdx.x;
  const int n = tid & 15, dl = tid >> 4;
  const int ch = blockIdx.x;
  const int d0 = blockIdx.y * 16;
  const int b  = blockIdx.z;
  const int d  = d0 + dl;
  const int t0 = ch * LC;
  const size_t brow = (size_t)b * SEQ;

  float u_r[4];
  #pragma unroll
  for (int i = 0; i < 4; i++) {               // cooperative coalesced staging
    int t = (tid >> 4) + i * 16;              // row within chunk
    size_t row = brow + t0 + t;
    float uval = xc [row * 256 + d0 + n];
    float dval = dtv[row * 256 + d0 + n];
    du2_s[t * 16 + n] = make_float2(dval, dval * uval);
    if constexpr (PASSC) {
      BC_s[t * 16 + n] = make_float2(xdbl[row * 48 + 16 + n],
                                     xdbl[row * 48 + 32 + n]);
      u_r[i] = uval;
    } else {
      Bc_s[t * 16 + n] = xdbl[row * 48 + 16 + n];
    }
  }
  __syncthreads();

  const float A_dn = -__expf(A_log[d * NST + n]);
  const size_t cidx = (((size_t)b * DM + d) * NST + n) * NCHK + ch;

  float h = PASSC ? Hstart[cidx] : 0.f;
  float P = 1.f;
  for (int t4 = 0; t4 < LC; t4 += 4) {
    float dA[4], dBu[4];
    #pragma unroll
    for (int j = 0; j < 4; j++) {             // independent: pipelined exps
      float2 du = du2_s[(t4 + j) * 16 + dl];
      dA[j] = __expf(du.x * A_dn);
      if constexpr (PASSC) dBu[j] = du.y;     // * B below
      else                 dBu[j] = du.y * Bc_s[(t4 + j) * 16 + n];
    }
    if constexpr (!PASSC) {
      #pragma unroll
      for (int j = 0; j < 4; j++) {
        h = fmaf(dA[j], h, dBu[j]);
        P *= dA[j];
      }
    } else {
      float yv[4];
      #pragma unroll
      for (int j = 0; j < 4; j++) {
        float2 bc = BC_s[(t4 + j) * 16 + n];
        h = fmaf(dA[j], h, dBu[j] * bc.x);
        yv[j] = h * bc.y;
      }
      // 16-lane row reduction on VALU (DPP); sum lands in lane 15.
      #pragma unroll
      for (int j = 0; j < 4; j++) yv[j] = dpp_add_step<0x118>(yv[j]); // shr8
      #pragma unroll
      for (int j = 0; j < 4; j++) yv[j] = dpp_add_step<0x114>(yv[j]); // shr4
      #pragma unroll
      for (int j = 0; j < 4; j++) yv[j] = dpp_add_step<0x112>(yv[j]); // shr2
      #pragma unroll
      for (int j = 0; j < 4; j++) yv[j] = dpp_add_step<0x111>(yv[j]); // shr1
      if (n == 15)
        *(float4*)&y_s[dl * 65 + t4] = make_float4(yv[0], yv[1], yv[2], yv[3]);
    }
  }

  if constexpr (!PASSC) {
    Pbuf[cidx] = P;
    hfbuf[cidx] = h;
  } else {
    __syncthreads();
    const float Dval = Dp[d0 + n];
    #pragma unroll
    for (int i = 0; i < 4; i++) {             // coalesced writeback
      int t = (tid >> 4) + i * 16;
      pout[(brow + t0 + t) * 256 + d0 + n] = fmaf(Dval, u_r[i], y_s[n * 65 + t]);
    }
  }
}

// serial combine across the 64 chunks; one thread per (b,d,n) chain
__global__ __launch_bounds__(256)
void scan_mid_k(const float* __restrict__ Pbuf, const float* __restrict__ hfbuf,
                float* __restrict__ Hstart)
{
  int tid = blockIdx.x * 256 + threadIdx.x;   // 0..16383
  size_t base = (size_t)tid * NCHK;
  float H = 0.f;
  for (int c = 0; c < NCHK; c++) {
    Hstart[base + c] = H;
    H = Pbuf[base + c] * H + hfbuf[base + c];
  }
}

// ---------------------------------------------------------------------------
extern "C" void kernel_launch(void* const* d_in, const int* in_sizes, int n_in,
                              void* d_out, int out_size, void* d_ws, size_t ws_size,
                              hipStream_t stream)
{
  const float* hs    = (const float*)d_in[0];
  const float* w_in  = (const float*)d_in[1];
  const float* w_xp  = (const float*)d_in[2];
  const float* w_dt  = (const float*)d_in[3];
  const float* b_dt  = (const float*)d_in[4];
  const float* A_log = (const float*)d_in[5];
  const float* Dp    = (const float*)d_in[6];
  const float* w_o1  = (const float*)d_in[7];
  const float* cwx   = (const float*)d_in[8];
  const float* cbx   = (const float*)d_in[9];
  const float* cwy   = (const float*)d_in[10];
  const float* cby   = (const float*)d_in[11];
  const float* cwz   = (const float*)d_in[12];
  const float* cbz   = (const float*)d_in[13];

  float* ws = (float*)d_ws;
  float* xyz  = ws;                                   // MT*768
  float* xc   = ws  + (size_t)MT * 768;               // MT*256
  float* yc   = xc  + (size_t)MT * 256;               // MT*256
  float* zc   = yc  + (size_t)MT * 256;               // MT*256
  // reuse of region A (xyz dead after conv):
  float* xdbl = ws;                                   // MT*48
  float* dtv  = xdbl + (size_t)MT * 48;               // MT*256 (delta)
  float* pbuf = dtv  + (size_t)MT * 256;              // MT*256
  float* Pb   = pbuf + (size_t)MT * 256;
  float* hf   = Pb   + (size_t)B_SZ * DM * NST * NCHK;
  float* Hs   = hf   + (size_t)B_SZ * DM * NST * NCHK;

  dim3 blk(256);

  // K1: xyz[M,768] = hs @ in_proj_w^T      (bf16 MFMA)
  mfma_gemm_k<0, false><<<dim3(768 / 128, MT / 128), blk, 0, stream>>>(
      hs, nullptr, w_in, xyz, 768, 256, nullptr, nullptr, nullptr);

  // K2: depthwise conv + SiLU -> xc, yc, zc  (b,l,d), register-window
  conv_silu_k<<<dim3((MT / CT) * 192 / 256), blk, 0, stream>>>(
      (const float4*)xyz, cwx, cbx, cwy, cby, cwz, cbz,
      (float4*)xc, (float4*)yc, (float4*)zc);

  // K3: x_dbl[M,48] = xc @ x_proj_w^T
  gemm_k<0><<<dim3(1, MT / 64), blk, 0, stream>>>(
      xc, w_xp, xdbl, MT, 48, 256, 256, nullptr);

  // K4: dtv[M,256] = softplus(x_dbl[:, :16] @ dt_proj_w^T + 2*dt_proj_b)
  gemm_k<3><<<dim3(256 / 64, MT / 64), blk, 0, stream>>>(
      xdbl, w_dt, dtv, MT, 256, 16, 48, b_dt);

  // K5-7: chunked selective scan -> pbuf (b,l,d)
  scan_k<false><<<dim3(NCHK, DM / 16, B_SZ), blk, 0, stream>>>(
      xc, dtv, xdbl, A_log, Dp, nullptr, Pb, hf, nullptr);
  scan_mid_k<<<dim3((B_SZ * DM * NST) / 256), blk, 0, stream>>>(Pb, hf, Hs);
  scan_k<true><<<dim3(NCHK, DM / 16, B_SZ), blk, 0, stream>>>(
      xc, dtv, xdbl, A_log, Dp, Hs, nullptr, nullptr, pbuf);

  // K8: out = ((pbuf*yc) @ out_proj1_w^T) * zc * cwx + cbx   (bf16 MFMA)
  mfma_gemm_k<2, true><<<dim3(256 / 128, MT / 128), blk, 0, stream>>>(
      pbuf, yc, w_o1, (float*)d_out, 256, 256, cbx, zc, cwx);
}

// Round 10
// 225.832 us; speedup vs baseline: 3.2811x; 1.0614x over previous
//
#include <hip/hip_runtime.h>
#include <hip/hip_bf16.h>
#include <math.h>

typedef __hip_bfloat16 bf16;
typedef __attribute__((ext_vector_type(8))) short bf16x8;
typedef __attribute__((ext_vector_type(4))) float f32x4;

#define B_SZ 4
#define SEQ  4096
#define DM   256
#define NST  16
#define NCHK 64
#define LC   (SEQ/NCHK)      /* 64 */
#define MT   (B_SZ*SEQ)      /* 16384 rows of (b,l) */
#define CT   4               /* l-tile per conv thread */

__device__ __forceinline__ float silu_f(float v){ return v / (1.f + __expf(-v)); }
__device__ __forceinline__ float softplus_f(float v){
  return (v > 15.f) ? v : __logf(1.f + __expf(v));
}
__device__ __forceinline__ short f2bf(float f){
  union { bf16 h; short s; } u; u.h = __float2bfloat16(f); return u.s;
}
__device__ __forceinline__ float bf2f(short s){
  union { unsigned int i; float f; } v;
  v.i = ((unsigned int)(unsigned short)s) << 16; return v.f;
}
__device__ __forceinline__ float4 bf4_to_f4(uint2 q){
  float4 f;
  f.x = bf2f((short)(q.x & 0xffffu)); f.y = bf2f((short)(q.x >> 16));
  f.z = bf2f((short)(q.y & 0xffffu)); f.w = bf2f((short)(q.y >> 16));
  return f;
}
__device__ __forceinline__ short4 f4_to_bf4(float4 f){
  short4 s; s.x = f2bf(f.x); s.y = f2bf(f.y); s.z = f2bf(f.z); s.w = f2bf(f.w);
  return s;
}

// DPP row_shr:N add step: lane i += lane(i-N) within its 16-lane row
// (invalid sources read 0). After N=8,4,2,1 lane 15 holds the row sum.
template<int CTRL>
__device__ __forceinline__ float dpp_add_step(float v){
  int x = __builtin_amdgcn_update_dpp(0, __float_as_int(v), CTRL, 0xf, 0xf, true);
  return v + __int_as_float(x);
}

// ---------------------------------------------------------------------------
// MFMA bf16 GEMM: Out[M,N] = (A[M,K] (* A2 elementwise)) @ Bw[N,K]^T.
// A: fp32 (ABF=0) or bf16 (ABF=1). Out: fp32 (OBF=0) or bf16 (OBF=1).
// Bw always fp32 (weight input). Block 256 = 4 waves (2x2), tile 128x128, BK=32.
// EPI 0: plain store. EPI 2: (acc * zc[m,n] * cwx[n] + bias[n]) (zc bf16).
// ---------------------------------------------------------------------------
template<int EPI, bool A2M, bool ABF, bool OBF>
__global__ __launch_bounds__(256)
void mfma_gemm_k(const void* __restrict__ Av, const void* __restrict__ A2v,
                 const float* __restrict__ Bw, void* __restrict__ Outv,
                 int N, int K,
                 const float* __restrict__ bias, const short* __restrict__ zc,
                 const float* __restrict__ cwx)
{
  constexpr int BM = 128, BN = 128, BK = 32, LDP = 40;  // pad 32->40 shorts
  __shared__ short As[BM * LDP];
  __shared__ short Bs[BN * LDP];
  const int tid  = threadIdx.x;
  const int wave = tid >> 6, lane = tid & 63;
  const int quad = lane >> 4, l16 = lane & 15;
  const int wm = (wave & 1) * 64, wn = (wave >> 1) * 64;
  const int m0 = blockIdx.y * BM, n0 = blockIdx.x * BN;
  const int srow = tid >> 3;            // 0..31 (row within 32-row pass)
  const int skq  = (tid & 7) * 4;       // k offset 0,4,..,28

  f32x4 acc[4][4] = {};

  for (int k0 = 0; k0 < K; k0 += BK) {
    #pragma unroll
    for (int p = 0; p < 4; p++) {
      int row = p * 32 + srow;
      size_t ga = (size_t)(m0 + row) * K + k0 + skq;
      float4 q;
      if constexpr (ABF) q = bf4_to_f4(*(const uint2*)((const short*)Av + ga));
      else               q = *(const float4*)((const float*)Av + ga);
      if constexpr (A2M) {
        float4 r = bf4_to_f4(*(const uint2*)((const short*)A2v + ga));
        q.x *= r.x; q.y *= r.y; q.z *= r.z; q.w *= r.w;
      }
      *(short4*)&As[row * LDP + skq] = f4_to_bf4(q);
      size_t gb = (size_t)(n0 + row) * K + k0 + skq;
      *(short4*)&Bs[row * LDP + skq] = f4_to_bf4(*(const float4*)(Bw + gb));
    }
    __syncthreads();
    bf16x8 fa[4], fb[4];
    #pragma unroll
    for (int i = 0; i < 4; i++) {
      fa[i] = *(const bf16x8*)&As[(wm + i * 16 + l16) * LDP + quad * 8];
      fb[i] = *(const bf16x8*)&Bs[(wn + i * 16 + l16) * LDP + quad * 8];
    }
    #pragma unroll
    for (int i = 0; i < 4; i++)
      #pragma unroll
      for (int j = 0; j < 4; j++)
        acc[i][j] = __builtin_amdgcn_mfma_f32_16x16x32_bf16(fa[i], fb[j], acc[i][j], 0, 0, 0);
    __syncthreads();
  }

  #pragma unroll
  for (int i = 0; i < 4; i++) {
    #pragma unroll
    for (int j = 0; j < 4; j++) {
      int n = n0 + wn + j * 16 + l16;
      #pragma unroll
      for (int r = 0; r < 4; r++) {
        int m = m0 + wm + i * 16 + quad * 4 + r;
        float v = acc[i][j][r];
        if constexpr (EPI == 2)
          v = v * bf2f(zc[(size_t)m * N + n]) * cwx[n] + bias[n];
        if constexpr (OBF) ((short*)Outv)[(size_t)m * N + n] = f2bf(v);
        else               ((float*)Outv)[(size_t)m * N + n] = v;
      }
    }
  }
}

// ---------------------------------------------------------------------------
// Vector-fp32 tiled GEMM (small shapes K3/K4). A: bf16 (ABF) or fp32.
// EPI 0: store fp32. EPI 3: fp32 store of softplus(acc + 2*bias[n]).
// ---------------------------------------------------------------------------
template<int EPI, bool ABF>
__global__ __launch_bounds__(256)
void gemm_k(const void* __restrict__ Av,
            const float* __restrict__ Bw, void* __restrict__ Out,
            int M, int N, int K, int lda,
            const float* __restrict__ bias)
{
  constexpr int TM = 64, TN = 64, TK = 16;
  __shared__ __align__(16) float As[TK][TM + 4];
  __shared__ __align__(16) float Bs[TK][TN + 4];
  const int tid = threadIdx.x;
  const int tn = tid & 15, tm = tid >> 4;
  const int n0 = blockIdx.x * TN, m0 = blockIdx.y * TM;
  float acc[4][4] = {};
  const int ml = tid >> 2;          // 0..63
  const int kq = (tid & 3) << 2;    // 0,4,8,12

  for (int k0 = 0; k0 < K; k0 += TK) {
    {
      size_t off = (size_t)(m0 + ml) * lda + k0 + kq;
      float4 q;
      if constexpr (ABF) q = bf4_to_f4(*(const uint2*)((const short*)Av + off));
      else               q = *(const float4*)((const float*)Av + off);
      As[kq+0][ml] = q.x; As[kq+1][ml] = q.y; As[kq+2][ml] = q.z; As[kq+3][ml] = q.w;
    }
    {
      float v0 = 0.f, v1 = 0.f, v2 = 0.f, v3 = 0.f;
      if (n0 + ml < N) {
        float4 q = *(const float4*)(Bw + (size_t)(n0 + ml) * K + k0 + kq);
        v0 = q.x; v1 = q.y; v2 = q.z; v3 = q.w;
      }
      Bs[kq+0][ml] = v0; Bs[kq+1][ml] = v1; Bs[kq+2][ml] = v2; Bs[kq+3][ml] = v3;
    }
    __syncthreads();
    #pragma unroll
    for (int k = 0; k < TK; k++) {
      float4 av = *(const float4*)&As[k][tm << 2];
      float4 bv = *(const float4*)&Bs[k][tn << 2];
      float a[4] = {av.x, av.y, av.z, av.w};
      float b[4] = {bv.x, bv.y, bv.z, bv.w};
      #pragma unroll
      for (int i = 0; i < 4; i++)
        #pragma unroll
        for (int j = 0; j < 4; j++)
          acc[i][j] = fmaf(a[i], b[j], acc[i][j]);
    }
    __syncthreads();
  }

  #pragma unroll
  for (int i = 0; i < 4; i++) {
    int m = m0 + (tm << 2) + i;
    #pragma unroll
    for (int j = 0; j < 4; j++) {
      int n = n0 + (tn << 2) + j;
      if (n < N) {
        float v = acc[i][j];
        if constexpr (EPI == 0) {
          ((float*)Out)[(size_t)m * N + n] = v;
        } else {
          ((float*)Out)[(size_t)m * N + n] = softplus_f(v + 2.f * bias[n]);
        }
      }
    }
  }
}

// ---------------------------------------------------------------------------
// Depthwise conv + SiLU, register-sliding-window, bf16 in / bf16 out.
// Thread = (c4, l-tile of CT). idx = lt*192 + c4: each wave spans one branch.
// ---------------------------------------------------------------------------
__global__ __launch_bounds__(256)
void conv_silu_k(const short* __restrict__ xyzb,   // (MT, 768) bf16
                 const float* __restrict__ wx, const float* __restrict__ bx,
                 const float* __restrict__ wy, const float* __restrict__ by,
                 const float* __restrict__ wz, const float* __restrict__ bz,
                 short* __restrict__ xcb, short* __restrict__ ycb,
                 short* __restrict__ zcb)
{
  int idx = blockIdx.x * 256 + threadIdx.x;     // over (MT/CT)*192
  int c4 = idx % 192;
  int lt = idx / 192;
  int row0 = lt * CT;                            // global (b*SEQ + l) base
  int l0 = row0 & (SEQ - 1);                     // l within batch

  float4 win[CT + 4];
  #pragma unroll
  for (int i = 0; i < CT + 4; i++) {
    int l = l0 + i - 2;
    if (l >= 0 && l < SEQ)
      win[i] = bf4_to_f4(*(const uint2*)(xyzb + (size_t)(row0 + i - 2) * 768 + c4 * 4));
    else
      win[i] = make_float4(0.f, 0.f, 0.f, 0.f);
  }

  if (c4 < 64) {                                 // x: k=1 pointwise
    int d = c4 * 4;
    float4 w  = *(const float4*)&wx[d];
    float4 bb = *(const float4*)&bx[d];
    #pragma unroll
    for (int t = 0; t < CT; t++) {
      float4 v = win[t + 2], o;
      o.x = silu_f(fmaf(v.x, w.x, bb.x));
      o.y = silu_f(fmaf(v.y, w.y, bb.y));
      o.z = silu_f(fmaf(v.z, w.z, bb.z));
      o.w = silu_f(fmaf(v.w, w.w, bb.w));
      *(short4*)&xcb[(size_t)(row0 + t) * 256 + d] = f4_to_bf4(o);
    }
  } else if (c4 < 128) {                         // y: k=3
    int d = (c4 - 64) * 4;
    float wq[4][3];
    #pragma unroll
    for (int q = 0; q < 4; q++)
      #pragma unroll
      for (int j = 0; j < 3; j++) wq[q][j] = wy[(d + q) * 3 + j];
    float4 bb = *(const float4*)&by[d];
    #pragma unroll
    for (int t = 0; t < CT; t++) {
      float a0 = bb.x, a1 = bb.y, a2 = bb.z, a3 = bb.w;
      #pragma unroll
      for (int j = 0; j < 3; j++) {
        float4 v = win[t + 1 + j];
        a0 = fmaf(v.x, wq[0][j], a0);
        a1 = fmaf(v.y, wq[1][j], a1);
        a2 = fmaf(v.z, wq[2][j], a2);
        a3 = fmaf(v.w, wq[3][j], a3);
      }
      float4 o; o.x = silu_f(a0); o.y = silu_f(a1); o.z = silu_f(a2); o.w = silu_f(a3);
      *(short4*)&ycb[(size_t)(row0 + t) * 256 + d] = f4_to_bf4(o);
    }
  } else {                                       // z: k=5
    int d = (c4 - 128) * 4;
    float wq[4][5];
    #pragma unroll
    for (int q = 0; q < 4; q++)
      #pragma unroll
      for (int j = 0; j < 5; j++) wq[q][j] = wz[(d + q) * 5 + j];
    float4 bb = *(const float4*)&bz[d];
    #pragma unroll
    for (int t = 0; t < CT; t++) {
      float a0 = bb.x, a1 = bb.y, a2 = bb.z, a3 = bb.w;
      #pragma unroll
      for (int j = 0; j < 5; j++) {
        float4 v = win[t + j];
        a0 = fmaf(v.x, wq[0][j], a0);
        a1 = fmaf(v.y, wq[1][j], a1);
        a2 = fmaf(v.z, wq[2][j], a2);
        a3 = fmaf(v.w, wq[3][j], a3);
      }
      float4 o; o.x = silu_f(a0); o.y = silu_f(a1); o.z = silu_f(a2); o.w = silu_f(a3);
      *(short4*)&zcb[(size_t)(row0 + t) * 256 + d] = f4_to_bf4(o);
    }
  }
}

// ---------------------------------------------------------------------------
// Chunked selective scan, t-unrolled x4, LDS-op-minimized (R7/R8 notes).
// u input bf16; pass C output bf16.
// ---------------------------------------------------------------------------
template<bool PASSC>
__global__ __launch_bounds__(256)
void scan_k(const short* __restrict__ xcb,    // u (bf16), (MT,256)
            const float* __restrict__ dtv,    // delta, (MT,256)
            const float* __restrict__ xdbl,   // (MT,48): [dt_r | B | C]
            const float* __restrict__ A_log,
            const float* __restrict__ Dp,
            const float* __restrict__ Hstart,
            float* __restrict__ Pbuf, float* __restrict__ hfbuf,
            short* __restrict__ poutb)        // pass C out (bf16), (MT,256)
{
  __shared__ float2 du2_s[LC * 16];                    // {delta, delta*u}[t][ch]
  __shared__ float2 BC_s [PASSC ? LC * 16 : 16];       // {B, C}[t][n]
  __shared__ float  Bc_s [PASSC ? 16 : LC * 16];       // B[t][n] (pass A)
  __shared__ float  y_s  [PASSC ? 16 * 65 : 16];       // y[ch][t], pad 65
  const int tid = threadIdx.x;
  const int n = tid & 15, dl = tid >> 4;
  const int ch = blockIdx.x;
  const int d0 = blockIdx.y * 16;
  const int b  = blockIdx.z;
  const int d  = d0 + dl;
  const int t0 = ch * LC;
  const size_t brow = (size_t)b * SEQ;

  float u_r[4];
  #pragma unroll
  for (int i = 0; i < 4; i++) {               // cooperative coalesced staging
    int t = (tid >> 4) + i * 16;              // row within chunk
    size_t row = brow + t0 + t;
    float uval = bf2f(xcb[row * 256 + d0 + n]);
    float dval = dtv[row * 256 + d0 + n];
    du2_s[t * 16 + n] = make_float2(dval, dval * uval);
    if constexpr (PASSC) {
      BC_s[t * 16 + n] = make_float2(xdbl[row * 48 + 16 + n],
                                     xdbl[row * 48 + 32 + n]);
      u_r[i] = uval;
    } else {
      Bc_s[t * 16 + n] = xdbl[row * 48 + 16 + n];
    }
  }
  __syncthreads();

  const float A_dn = -__expf(A_log[d * NST + n]);
  const size_t cidx = (((size_t)b * DM + d) * NST + n) * NCHK + ch;

  float h = PASSC ? Hstart[cidx] : 0.f;
  float P = 1.f;
  for (int t4 = 0; t4 < LC; t4 += 4) {
    float dA[4], dBu[4];
    #pragma unroll
    for (int j = 0; j < 4; j++) {             // independent: pipelined exps
      float2 du = du2_s[(t4 + j) * 16 + dl];
      dA[j] = __expf(du.x * A_dn);
      if constexpr (PASSC) dBu[j] = du.y;     // * B below
      else                 dBu[j] = du.y * Bc_s[(t4 + j) * 16 + n];
    }
    if constexpr (!PASSC) {
      #pragma unroll
      for (int j = 0; j < 4; j++) {
        h = fmaf(dA[j], h, dBu[j]);
        P *= dA[j];
      }
    } else {
      float yv[4];
      #pragma unroll
      for (int j = 0; j < 4; j++) {
        float2 bc = BC_s[(t4 + j) * 16 + n];
        h = fmaf(dA[j], h, dBu[j] * bc.x);
        yv[j] = h * bc.y;
      }
      // 16-lane row reduction on VALU (DPP); sum lands in lane 15.
      #pragma unroll
      for (int j = 0; j < 4; j++) yv[j] = dpp_add_step<0x118>(yv[j]); // shr8
      #pragma unroll
      for (int j = 0; j < 4; j++) yv[j] = dpp_add_step<0x114>(yv[j]); // shr4
      #pragma unroll
      for (int j = 0; j < 4; j++) yv[j] = dpp_add_step<0x112>(yv[j]); // shr2
      #pragma unroll
      for (int j = 0; j < 4; j++) yv[j] = dpp_add_step<0x111>(yv[j]); // shr1
      if (n == 15)
        *(float4*)&y_s[dl * 65 + t4] = make_float4(yv[0], yv[1], yv[2], yv[3]);
    }
  }

  if constexpr (!PASSC) {
    Pbuf[cidx] = P;
    hfbuf[cidx] = h;
  } else {
    __syncthreads();
    const float Dval = Dp[d0 + n];
    #pragma unroll
    for (int i = 0; i < 4; i++) {             // coalesced writeback
      int t = (tid >> 4) + i * 16;
      poutb[(brow + t0 + t) * 256 + d0 + n] =
          f2bf(fmaf(Dval, u_r[i], y_s[n * 65 + t]));
    }
  }
}

// serial combine across the 64 chunks; one thread per (b,d,n) chain
__global__ __launch_bounds__(256)
void scan_mid_k(const float* __restrict__ Pbuf, const float* __restrict__ hfbuf,
                float* __restrict__ Hstart)
{
  int tid = blockIdx.x * 256 + threadIdx.x;   // 0..16383
  size_t base = (size_t)tid * NCHK;
  float H = 0.f;
  for (int c = 0; c < NCHK; c++) {
    Hstart[base + c] = H;
    H = Pbuf[base + c] * H + hfbuf[base + c];
  }
}

// ---------------------------------------------------------------------------
extern "C" void kernel_launch(void* const* d_in, const int* in_sizes, int n_in,
                              void* d_out, int out_size, void* d_ws, size_t ws_size,
                              hipStream_t stream)
{
  const float* hs    = (const float*)d_in[0];
  const float* w_in  = (const float*)d_in[1];
  const float* w_xp  = (const float*)d_in[2];
  const float* w_dt  = (const float*)d_in[3];
  const float* b_dt  = (const float*)d_in[4];
  const float* A_log = (const float*)d_in[5];
  const float* Dp    = (const float*)d_in[6];
  const float* w_o1  = (const float*)d_in[7];
  const float* cwx   = (const float*)d_in[8];
  const float* cbx   = (const float*)d_in[9];
  const float* cwy   = (const float*)d_in[10];
  const float* cby   = (const float*)d_in[11];
  const float* cwz   = (const float*)d_in[12];
  const float* cbz   = (const float*)d_in[13];

  char* wsb = (char*)d_ws;
  short* xyzb = (short*)wsb;                            // MT*768 bf16 (24 MB)
  short* xcb  = (short*)(wsb + (size_t)MT * 768 * 2);   // MT*256 bf16
  short* ycb  = xcb + (size_t)MT * 256;                 // MT*256 bf16
  short* zcb  = ycb + (size_t)MT * 256;                 // MT*256 bf16
  short* pbufb= zcb + (size_t)MT * 256;                 // MT*256 bf16
  float* xdbl = (float*)(pbufb + (size_t)MT * 256);     // MT*48 fp32
  float* dtv  = xdbl + (size_t)MT * 48;                 // MT*256 fp32
  float* Pb   = dtv  + (size_t)MT * 256;                // 1M fp32
  float* hf   = Pb   + (size_t)B_SZ * DM * NST * NCHK;
  float* Hs   = hf   + (size_t)B_SZ * DM * NST * NCHK;

  dim3 blk(256);

  // K1: xyz[M,768] = hs @ in_proj_w^T      (bf16 MFMA, bf16 out)
  mfma_gemm_k<0, false, false, true><<<dim3(768 / 128, MT / 128), blk, 0, stream>>>(
      hs, nullptr, w_in, xyzb, 768, 256, nullptr, nullptr, nullptr);

  // K2: depthwise conv + SiLU -> xcb, ycb, zcb (bf16)
  conv_silu_k<<<dim3((MT / CT) * 192 / 256), blk, 0, stream>>>(
      xyzb, cwx, cbx, cwy, cby, cwz, cbz, xcb, ycb, zcb);

  // K3: x_dbl[M,48] = xc @ x_proj_w^T  (A bf16)
  gemm_k<0, true><<<dim3(1, MT / 64), blk, 0, stream>>>(
      xcb, w_xp, xdbl, MT, 48, 256, 256, nullptr);

  // K4: dtv[M,256] = softplus(x_dbl[:, :16] @ dt_proj_w^T + 2*dt_proj_b)
  gemm_k<3, false><<<dim3(256 / 64, MT / 64), blk, 0, stream>>>(
      xdbl, w_dt, dtv, MT, 256, 16, 48, b_dt);

  // K5-7: chunked selective scan -> pbufb (bf16)
  scan_k<false><<<dim3(NCHK, DM / 16, B_SZ), blk, 0, stream>>>(
      xcb, dtv, xdbl, A_log, Dp, nullptr, Pb, hf, nullptr);
  scan_mid_k<<<dim3((B_SZ * DM * NST) / 256), blk, 0, stream>>>(Pb, hf, Hs);
  scan_k<true><<<dim3(NCHK, DM / 16, B_SZ), blk, 0, stream>>>(
      xcb, dtv, xdbl, A_log, Dp, Hs, nullptr, nullptr, pbufb);

  // K8: out = ((pbuf*yc) @ out_proj1_w^T) * zc * cwx + cbx  (fp32 out)
  mfma_gemm_k<2, true, true, false><<<dim3(256 / 128, MT / 128), blk, 0, stream>>>(
      pbufb, ycb, w_o1, (float*)d_out, 256, 256, cbx, zcb, cwx);
}

// Round 11
// 219.323 us; speedup vs baseline: 3.3784x; 1.0297x over previous
//
#include <hip/hip_runtime.h>
#include <hip/hip_bf16.h>
#include <math.h>

typedef __hip_bfloat16 bf16;
typedef __attribute__((ext_vector_type(8))) short bf16x8;
typedef __attribute__((ext_vector_type(4))) float f32x4;

#define B_SZ 4
#define SEQ  4096
#define DM   256
#define NST  16
#define NCHK 64
#define LC   (SEQ/NCHK)      /* 64 */
#define MT   (B_SZ*SEQ)      /* 16384 rows of (b,l) */
#define CT   4               /* l-tile per conv thread */

__device__ __forceinline__ float silu_f(float v){ return v / (1.f + __expf(-v)); }
__device__ __forceinline__ float softplus_f(float v){
  return (v > 15.f) ? v : __logf(1.f + __expf(v));
}
__device__ __forceinline__ short f2bf(float f){
  union { bf16 h; short s; } u; u.h = __float2bfloat16(f); return u.s;
}
__device__ __forceinline__ float bf2f(short s){
  union { unsigned int i; float f; } v;
  v.i = ((unsigned int)(unsigned short)s) << 16; return v.f;
}
__device__ __forceinline__ float4 bf4_to_f4(uint2 q){
  float4 f;
  f.x = bf2f((short)(q.x & 0xffffu)); f.y = bf2f((short)(q.x >> 16));
  f.z = bf2f((short)(q.y & 0xffffu)); f.w = bf2f((short)(q.y >> 16));
  return f;
}
__device__ __forceinline__ short4 f4_to_bf4(float4 f){
  short4 s; s.x = f2bf(f.x); s.y = f2bf(f.y); s.z = f2bf(f.z); s.w = f2bf(f.w);
  return s;
}

// DPP row_shr:N add step; after N=8,4,2,1 lane 15 of each row = row sum.
template<int CTRL>
__device__ __forceinline__ float dpp_add_step(float v){
  int x = __builtin_amdgcn_update_dpp(0, __float_as_int(v), CTRL, 0xf, 0xf, true);
  return v + __int_as_float(x);
}

// ---------------------------------------------------------------------------
// MFMA bf16 GEMM. Grid (m-tiles, n-tiles): m on blockIdx.x so same-m blocks
// share an XCD (flat = y*gridX + x, gridX % 8 == 0) -> A re-reads hit L2.
// A: fp32 (ABF=0) or bf16 (ABF=1). Out per OBF. Bw fp32.
// EPI 0: plain store. EPI 2: (acc * zc[m,n] * cwx[n] + bias[n]) (zc bf16).
// ---------------------------------------------------------------------------
template<int EPI, bool A2M, bool ABF, bool OBF>
__global__ __launch_bounds__(256)
void mfma_gemm_k(const void* __restrict__ Av, const void* __restrict__ A2v,
                 const float* __restrict__ Bw, void* __restrict__ Outv,
                 int N, int K,
                 const float* __restrict__ bias, const short* __restrict__ zc,
                 const float* __restrict__ cwx)
{
  constexpr int BM = 128, BN = 128, BK = 32, LDP = 40;  // pad 32->40 shorts
  __shared__ short As[BM * LDP];
  __shared__ short Bs[BN * LDP];
  const int tid  = threadIdx.x;
  const int wave = tid >> 6, lane = tid & 63;
  const int quad = lane >> 4, l16 = lane & 15;
  const int wm = (wave & 1) * 64, wn = (wave >> 1) * 64;
  const int m0 = blockIdx.x * BM, n0 = blockIdx.y * BN;   // m-major (XCD reuse)
  const int srow = tid >> 3;            // 0..31
  const int skq  = (tid & 7) * 4;       // 0,4,..,28

  f32x4 acc[4][4] = {};

  for (int k0 = 0; k0 < K; k0 += BK) {
    #pragma unroll
    for (int p = 0; p < 4; p++) {
      int row = p * 32 + srow;
      size_t ga = (size_t)(m0 + row) * K + k0 + skq;
      float4 q;
      if constexpr (ABF) q = bf4_to_f4(*(const uint2*)((const short*)Av + ga));
      else               q = *(const float4*)((const float*)Av + ga);
      if constexpr (A2M) {
        float4 r = bf4_to_f4(*(const uint2*)((const short*)A2v + ga));
        q.x *= r.x; q.y *= r.y; q.z *= r.z; q.w *= r.w;
      }
      *(short4*)&As[row * LDP + skq] = f4_to_bf4(q);
      size_t gb = (size_t)(n0 + row) * K + k0 + skq;
      *(short4*)&Bs[row * LDP + skq] = f4_to_bf4(*(const float4*)(Bw + gb));
    }
    __syncthreads();
    bf16x8 fa[4], fb[4];
    #pragma unroll
    for (int i = 0; i < 4; i++) {
      fa[i] = *(const bf16x8*)&As[(wm + i * 16 + l16) * LDP + quad * 8];
      fb[i] = *(const bf16x8*)&Bs[(wn + i * 16 + l16) * LDP + quad * 8];
    }
    #pragma unroll
    for (int i = 0; i < 4; i++)
      #pragma unroll
      for (int j = 0; j < 4; j++)
        acc[i][j] = __builtin_amdgcn_mfma_f32_16x16x32_bf16(fa[i], fb[j], acc[i][j], 0, 0, 0);
    __syncthreads();
  }

  #pragma unroll
  for (int i = 0; i < 4; i++) {
    #pragma unroll
    for (int j = 0; j < 4; j++) {
      int n = n0 + wn + j * 16 + l16;
      #pragma unroll
      for (int r = 0; r < 4; r++) {
        int m = m0 + wm + i * 16 + quad * 4 + r;
        float v = acc[i][j][r];
        if constexpr (EPI == 2)
          v = v * bf2f(zc[(size_t)m * N + n]) * cwx[n] + bias[n];
        if constexpr (OBF) ((short*)Outv)[(size_t)m * N + n] = f2bf(v);
        else               ((float*)Outv)[(size_t)m * N + n] = v;
      }
    }
  }
}

// ---------------------------------------------------------------------------
// Fused K3+K4: phase 1 xdbl[M,48] = xc @ x_proj_w^T (A bf16), stashing dt_r
// cols in LDS; phase 2 dtv[M,256] = softplus(dt_r @ dt_proj_w^T + 2*b_dt).
// ---------------------------------------------------------------------------
__global__ __launch_bounds__(256)
void gemm34_k(const short* __restrict__ xcb,   // (MT,256) bf16
              const float* __restrict__ Bw,    // x_proj_w (48,256)
              const float* __restrict__ wdt,   // dt_proj_w (256,16)
              const float* __restrict__ bdt,   // dt_proj_b (256)
              float* __restrict__ xdbl,        // (MT,48)
              float* __restrict__ dtv)         // (MT,256)
{
  constexpr int TM = 64, TK = 16, NN = 48;
  __shared__ __align__(16) float As[TK][TM + 4];
  __shared__ __align__(16) float Bs[TK][TM + 4];
  __shared__ __align__(16) float dt_s[TM][20];
  __shared__ __align__(16) float wdt_s[256][20];
  const int tid = threadIdx.x;
  const int tn = tid & 15, tm = tid >> 4;
  const int m0 = blockIdx.x * TM;
  float acc[4][4] = {};
  const int ml = tid >> 2;          // 0..63
  const int kq = (tid & 3) << 2;    // 0,4,8,12

  { // stage w_dt (256x16) -> LDS, one row per thread
    float4 q0 = *(const float4*)&wdt[tid * 16 + 0];
    float4 q1 = *(const float4*)&wdt[tid * 16 + 4];
    float4 q2 = *(const float4*)&wdt[tid * 16 + 8];
    float4 q3 = *(const float4*)&wdt[tid * 16 + 12];
    *(float4*)&wdt_s[tid][0]  = q0;
    *(float4*)&wdt_s[tid][4]  = q1;
    *(float4*)&wdt_s[tid][8]  = q2;
    *(float4*)&wdt_s[tid][12] = q3;
  }

  for (int k0 = 0; k0 < 256; k0 += TK) {
    {
      size_t off = (size_t)(m0 + ml) * 256 + k0 + kq;
      float4 q = bf4_to_f4(*(const uint2*)(xcb + off));
      As[kq+0][ml] = q.x; As[kq+1][ml] = q.y; As[kq+2][ml] = q.z; As[kq+3][ml] = q.w;
    }
    {
      float v0 = 0.f, v1 = 0.f, v2 = 0.f, v3 = 0.f;
      if (ml < NN) {
        float4 q = *(const float4*)(Bw + (size_t)ml * 256 + k0 + kq);
        v0 = q.x; v1 = q.y; v2 = q.z; v3 = q.w;
      }
      Bs[kq+0][ml] = v0; Bs[kq+1][ml] = v1; Bs[kq+2][ml] = v2; Bs[kq+3][ml] = v3;
    }
    __syncthreads();
    #pragma unroll
    for (int k = 0; k < TK; k++) {
      float4 av = *(const float4*)&As[k][tm << 2];
      float4 bv = *(const float4*)&Bs[k][tn << 2];
      float a[4] = {av.x, av.y, av.z, av.w};
      float b[4] = {bv.x, bv.y, bv.z, bv.w};
      #pragma unroll
      for (int i = 0; i < 4; i++)
        #pragma unroll
        for (int j = 0; j < 4; j++)
          acc[i][j] = fmaf(a[i], b[j], acc[i][j]);
    }
    __syncthreads();
  }

  #pragma unroll
  for (int i = 0; i < 4; i++) {
    int m = m0 + (tm << 2) + i;
    #pragma unroll
    for (int j = 0; j < 4; j++) {
      int n = (tn << 2) + j;
      float v = acc[i][j];
      if (n < NN) xdbl[(size_t)m * NN + n] = v;
      if (tn < 4) dt_s[(tm << 2) + i][n] = v;   // dt_r cols 0..15
    }
  }
  __syncthreads();

  // phase 2: dtv[64 x 256] = softplus(dt_s @ wdt_s^T + 2*bdt)
  const int c0 = tid & 63, rg = tid >> 6;
  float w[4][16];
  float bb[4];
  #pragma unroll
  for (int cc = 0; cc < 4; cc++) {
    int col = cc * 64 + c0;
    #pragma unroll
    for (int q = 0; q < 4; q++) {
      float4 t = *(const float4*)&wdt_s[col][q * 4];
      w[cc][q*4+0] = t.x; w[cc][q*4+1] = t.y; w[cc][q*4+2] = t.z; w[cc][q*4+3] = t.w;
    }
    bb[cc] = 2.f * bdt[col];
  }
  #pragma unroll
  for (int rr = 0; rr < 16; rr++) {
    int row = rg * 16 + rr;
    float dr[16];
    #pragma unroll
    for (int q = 0; q < 4; q++) {
      float4 t = *(const float4*)&dt_s[row][q * 4];
      dr[q*4+0] = t.x; dr[q*4+1] = t.y; dr[q*4+2] = t.z; dr[q*4+3] = t.w;
    }
    #pragma unroll
    for (int cc = 0; cc < 4; cc++) {
      float s = bb[cc];
      #pragma unroll
      for (int k = 0; k < 16; k++) s = fmaf(dr[k], w[cc][k], s);
      dtv[(size_t)(m0 + row) * 256 + cc * 64 + c0] = softplus_f(s);
    }
  }
}

// ---------------------------------------------------------------------------
// Depthwise conv + SiLU, register-sliding-window, bf16 in / bf16 out.
// ---------------------------------------------------------------------------
__global__ __launch_bounds__(256)
void conv_silu_k(const short* __restrict__ xyzb,   // (MT, 768) bf16
                 const float* __restrict__ wx, const float* __restrict__ bx,
                 const float* __restrict__ wy, const float* __restrict__ by,
                 const float* __restrict__ wz, const float* __restrict__ bz,
                 short* __restrict__ xcb, short* __restrict__ ycb,
                 short* __restrict__ zcb)
{
  int idx = blockIdx.x * 256 + threadIdx.x;     // over (MT/CT)*192
  int c4 = idx % 192;
  int lt = idx / 192;
  int row0 = lt * CT;
  int l0 = row0 & (SEQ - 1);

  float4 win[CT + 4];
  #pragma unroll
  for (int i = 0; i < CT + 4; i++) {
    int l = l0 + i - 2;
    if (l >= 0 && l < SEQ)
      win[i] = bf4_to_f4(*(const uint2*)(xyzb + (size_t)(row0 + i - 2) * 768 + c4 * 4));
    else
      win[i] = make_float4(0.f, 0.f, 0.f, 0.f);
  }

  if (c4 < 64) {                                 // x: k=1 pointwise
    int d = c4 * 4;
    float4 w  = *(const float4*)&wx[d];
    float4 bb = *(const float4*)&bx[d];
    #pragma unroll
    for (int t = 0; t < CT; t++) {
      float4 v = win[t + 2], o;
      o.x = silu_f(fmaf(v.x, w.x, bb.x));
      o.y = silu_f(fmaf(v.y, w.y, bb.y));
      o.z = silu_f(fmaf(v.z, w.z, bb.z));
      o.w = silu_f(fmaf(v.w, w.w, bb.w));
      *(short4*)&xcb[(size_t)(row0 + t) * 256 + d] = f4_to_bf4(o);
    }
  } else if (c4 < 128) {                         // y: k=3
    int d = (c4 - 64) * 4;
    float wq[4][3];
    #pragma unroll
    for (int q = 0; q < 4; q++)
      #pragma unroll
      for (int j = 0; j < 3; j++) wq[q][j] = wy[(d + q) * 3 + j];
    float4 bb = *(const float4*)&by[d];
    #pragma unroll
    for (int t = 0; t < CT; t++) {
      float a0 = bb.x, a1 = bb.y, a2 = bb.z, a3 = bb.w;
      #pragma unroll
      for (int j = 0; j < 3; j++) {
        float4 v = win[t + 1 + j];
        a0 = fmaf(v.x, wq[0][j], a0);
        a1 = fmaf(v.y, wq[1][j], a1);
        a2 = fmaf(v.z, wq[2][j], a2);
        a3 = fmaf(v.w, wq[3][j], a3);
      }
      float4 o; o.x = silu_f(a0); o.y = silu_f(a1); o.z = silu_f(a2); o.w = silu_f(a3);
      *(short4*)&ycb[(size_t)(row0 + t) * 256 + d] = f4_to_bf4(o);
    }
  } else {                                       // z: k=5
    int d = (c4 - 128) * 4;
    float wq[4][5];
    #pragma unroll
    for (int q = 0; q < 4; q++)
      #pragma unroll
      for (int j = 0; j < 5; j++) wq[q][j] = wz[(d + q) * 5 + j];
    float4 bb = *(const float4*)&bz[d];
    #pragma unroll
    for (int t = 0; t < CT; t++) {
      float a0 = bb.x, a1 = bb.y, a2 = bb.z, a3 = bb.w;
      #pragma unroll
      for (int j = 0; j < 5; j++) {
        float4 v = win[t + j];
        a0 = fmaf(v.x, wq[0][j], a0);
        a1 = fmaf(v.y, wq[1][j], a1);
        a2 = fmaf(v.z, wq[2][j], a2);
        a3 = fmaf(v.w, wq[3][j], a3);
      }
      float4 o; o.x = silu_f(a0); o.y = silu_f(a1); o.z = silu_f(a2); o.w = silu_f(a3);
      *(short4*)&zcb[(size_t)(row0 + t) * 256 + d] = f4_to_bf4(o);
    }
  }
}

// ---------------------------------------------------------------------------
// Chunked selective scan, t-unrolled x4. LDS transposed to [channel][t]
// (pads 66/68: 16B alignment, <=2-way banks) -> 2 ds_read_b128 (du2) + 2 (BC)
// per t4 [pass C], or +1 (B) [pass A].
// ---------------------------------------------------------------------------
template<bool PASSC>
__global__ __launch_bounds__(256)
void scan_k(const short* __restrict__ xcb,    // u (bf16), (MT,256)
            const float* __restrict__ dtv,    // delta, (MT,256)
            const float* __restrict__ xdbl,   // (MT,48): [dt_r | B | C]
            const float* __restrict__ A_log,
            const float* __restrict__ Dp,
            const float* __restrict__ Hstart,
            float* __restrict__ Pbuf, float* __restrict__ hfbuf,
            short* __restrict__ poutb)        // pass C out (bf16), (MT,256)
{
  __shared__ __align__(16) float2 du2_s[16 * 66];             // [ch][t]
  __shared__ __align__(16) float2 BC_s [PASSC ? 16 * 66 : 2]; // [n][t]
  __shared__ __align__(16) float  Bc_s [PASSC ? 4 : 16 * 68]; // [n][t] (pass A)
  __shared__ __align__(16) float  y_s  [PASSC ? 16 * 68 : 4]; // [ch][t]
  const int tid = threadIdx.x;
  const int n = tid & 15, dl = tid >> 4;
  const int ch = blockIdx.x;
  const int d0 = blockIdx.y * 16;
  const int b  = blockIdx.z;
  const int d  = d0 + dl;
  const int t0 = ch * LC;
  const size_t brow = (size_t)b * SEQ;

  float u_r[4];
  #pragma unroll
  for (int i = 0; i < 4; i++) {               // cooperative coalesced staging
    int t = (tid >> 4) + i * 16;
    int dd = tid & 15;
    size_t row = brow + t0 + t;
    float uval = bf2f(xcb[row * 256 + d0 + dd]);
    float dval = dtv[row * 256 + d0 + dd];
    du2_s[dd * 66 + t] = make_float2(dval, dval * uval);
    if constexpr (PASSC) {
      BC_s[dd * 66 + t] = make_float2(xdbl[row * 48 + 16 + dd],
                                      xdbl[row * 48 + 32 + dd]);
      u_r[i] = uval;
    } else {
      Bc_s[dd * 68 + t] = xdbl[row * 48 + 16 + dd];
    }
  }
  __syncthreads();

  const float A_dn = -__expf(A_log[d * NST + n]);
  const size_t cidx = (((size_t)b * DM + d) * NST + n) * NCHK + ch;

  float h = PASSC ? Hstart[cidx] : 0.f;
  float P = 1.f;
  for (int t4 = 0; t4 < LC; t4 += 4) {
    float4 a = *(const float4*)&du2_s[dl * 66 + t4];      // {dt0,du0,dt1,du1}
    float4 c = *(const float4*)&du2_s[dl * 66 + t4 + 2];  // {dt2,du2,dt3,du3}
    float dA[4], du[4];
    dA[0] = __expf(a.x * A_dn); du[0] = a.y;
    dA[1] = __expf(a.z * A_dn); du[1] = a.w;
    dA[2] = __expf(c.x * A_dn); du[2] = c.y;
    dA[3] = __expf(c.z * A_dn); du[3] = c.w;
    if constexpr (!PASSC) {
      float4 f = *(const float4*)&Bc_s[n * 68 + t4];      // B t4..t4+3
      float Bv[4] = {f.x, f.y, f.z, f.w};
      #pragma unroll
      for (int j = 0; j < 4; j++) {
        h = fmaf(dA[j], h, du[j] * Bv[j]);
        P *= dA[j];
      }
    } else {
      float4 e = *(const float4*)&BC_s[n * 66 + t4];      // {B0,C0,B1,C1}
      float4 g = *(const float4*)&BC_s[n * 66 + t4 + 2];  // {B2,C2,B3,C3}
      float Bv[4] = {e.x, e.z, g.x, g.z};
      float Cv[4] = {e.y, e.w, g.y, g.w};
      float yv[4];
      #pragma unroll
      for (int j = 0; j < 4; j++) {
        h = fmaf(dA[j], h, du[j] * Bv[j]);
        yv[j] = h * Cv[j];
      }
      #pragma unroll
      for (int j = 0; j < 4; j++) yv[j] = dpp_add_step<0x118>(yv[j]); // shr8
      #pragma unroll
      for (int j = 0; j < 4; j++) yv[j] = dpp_add_step<0x114>(yv[j]); // shr4
      #pragma unroll
      for (int j = 0; j < 4; j++) yv[j] = dpp_add_step<0x112>(yv[j]); // shr2
      #pragma unroll
      for (int j = 0; j < 4; j++) yv[j] = dpp_add_step<0x111>(yv[j]); // shr1
      if (n == 15)
        *(float4*)&y_s[dl * 68 + t4] = make_float4(yv[0], yv[1], yv[2], yv[3]);
    }
  }

  if constexpr (!PASSC) {
    Pbuf[cidx] = P;
    hfbuf[cidx] = h;
  } else {
    __syncthreads();
    const float Dval = Dp[d0 + n];
    #pragma unroll
    for (int i = 0; i < 4; i++) {             // coalesced writeback
      int t = (tid >> 4) + i * 16;
      poutb[(brow + t0 + t) * 256 + d0 + n] =
          f2bf(fmaf(Dval, u_r[i], y_s[n * 68 + t]));
    }
  }
}

// serial combine across the 64 chunks; one thread per (b,d,n) chain
__global__ __launch_bounds__(256)
void scan_mid_k(const float* __restrict__ Pbuf, const float* __restrict__ hfbuf,
                float* __restrict__ Hstart)
{
  int tid = blockIdx.x * 256 + threadIdx.x;   // 0..16383
  size_t base = (size_t)tid * NCHK;
  float H = 0.f;
  for (int c = 0; c < NCHK; c++) {
    Hstart[base + c] = H;
    H = Pbuf[base + c] * H + hfbuf[base + c];
  }
}

// ---------------------------------------------------------------------------
extern "C" void kernel_launch(void* const* d_in, const int* in_sizes, int n_in,
                              void* d_out, int out_size, void* d_ws, size_t ws_size,
                              hipStream_t stream)
{
  const float* hs    = (const float*)d_in[0];
  const float* w_in  = (const float*)d_in[1];
  const float* w_xp  = (const float*)d_in[2];
  const float* w_dt  = (const float*)d_in[3];
  const float* b_dt  = (const float*)d_in[4];
  const float* A_log = (const float*)d_in[5];
  const float* Dp    = (const float*)d_in[6];
  const float* w_o1  = (const float*)d_in[7];
  const float* cwx   = (const float*)d_in[8];
  const float* cbx   = (const float*)d_in[9];
  const float* cwy   = (const float*)d_in[10];
  const float* cby   = (const float*)d_in[11];
  const float* cwz   = (const float*)d_in[12];
  const float* cbz   = (const float*)d_in[13];

  char* wsb = (char*)d_ws;
  short* xyzb = (short*)wsb;                            // MT*768 bf16
  short* xcb  = (short*)(wsb + (size_t)MT * 768 * 2);   // MT*256 bf16
  short* ycb  = xcb + (size_t)MT * 256;                 // MT*256 bf16
  short* zcb  = ycb + (size_t)MT * 256;                 // MT*256 bf16
  short* pbufb= zcb + (size_t)MT * 256;                 // MT*256 bf16
  float* xdbl = (float*)(pbufb + (size_t)MT * 256);     // MT*48 fp32
  float* dtv  = xdbl + (size_t)MT * 48;                 // MT*256 fp32
  float* Pb   = dtv  + (size_t)MT * 256;                // 1M fp32
  float* hf   = Pb   + (size_t)B_SZ * DM * NST * NCHK;
  float* Hs   = hf   + (size_t)B_SZ * DM * NST * NCHK;

  dim3 blk(256);

  // K1: xyz = hs @ in_proj_w^T  (bf16 MFMA, bf16 out; m-major grid)
  mfma_gemm_k<0, false, false, true><<<dim3(MT / 128, 768 / 128), blk, 0, stream>>>(
      hs, nullptr, w_in, xyzb, 768, 256, nullptr, nullptr, nullptr);

  // K2: depthwise conv + SiLU -> xcb, ycb, zcb (bf16)
  conv_silu_k<<<dim3((MT / CT) * 192 / 256), blk, 0, stream>>>(
      xyzb, cwx, cbx, cwy, cby, cwz, cbz, xcb, ycb, zcb);

  // K3+K4 fused
  gemm34_k<<<dim3(MT / 64), blk, 0, stream>>>(
      xcb, w_xp, w_dt, b_dt, xdbl, dtv);

  // K5-7: chunked selective scan -> pbufb (bf16)
  scan_k<false><<<dim3(NCHK, DM / 16, B_SZ), blk, 0, stream>>>(
      xcb, dtv, xdbl, A_log, Dp, nullptr, Pb, hf, nullptr);
  scan_mid_k<<<dim3((B_SZ * DM * NST) / 256), blk, 0, stream>>>(Pb, hf, Hs);
  scan_k<true><<<dim3(NCHK, DM / 16, B_SZ), blk, 0, stream>>>(
      xcb, dtv, xdbl, A_log, Dp, Hs, nullptr, nullptr, pbufb);

  // K8: out = ((pbuf*yc) @ out_proj1_w^T) * zc * cwx + cbx  (fp32 out)
  mfma_gemm_k<2, true, true, false><<<dim3(MT / 128, 256 / 128), blk, 0, stream>>>(
      pbufb, ycb, w_o1, (float*)d_out, 256, 256, cbx, zcb, cwx);
}

// Round 12
// 208.638 us; speedup vs baseline: 3.5515x; 1.0512x over previous
//
#include <hip/hip_runtime.h>
#include <hip/hip_bf16.h>
#include <math.h>

typedef __hip_bfloat16 bf16;
typedef __attribute__((ext_vector_type(8))) short bf16x8;
typedef __attribute__((ext_vector_type(4))) float f32x4;

#define B_SZ 4
#define SEQ  4096
#define DM   256
#define NST  16
#define NCHK 64
#define LC   (SEQ/NCHK)      /* 64 */
#define MT   (B_SZ*SEQ)      /* 16384 rows of (b,l) */
#define CT   4               /* l-tile per conv thread */

__device__ __forceinline__ float silu_f(float v){ return v / (1.f + __expf(-v)); }
__device__ __forceinline__ float softplus_f(float v){
  return (v > 15.f) ? v : __logf(1.f + __expf(v));
}
__device__ __forceinline__ short f2bf(float f){
  union { bf16 h; short s; } u; u.h = __float2bfloat16(f); return u.s;
}
__device__ __forceinline__ float bf2f(short s){
  union { unsigned int i; float f; } v;
  v.i = ((unsigned int)(unsigned short)s) << 16; return v.f;
}
__device__ __forceinline__ float4 bf4_to_f4(uint2 q){
  float4 f;
  f.x = bf2f((short)(q.x & 0xffffu)); f.y = bf2f((short)(q.x >> 16));
  f.z = bf2f((short)(q.y & 0xffffu)); f.w = bf2f((short)(q.y >> 16));
  return f;
}
__device__ __forceinline__ short4 f4_to_bf4(float4 f){
  short4 s; s.x = f2bf(f.x); s.y = f2bf(f.y); s.z = f2bf(f.z); s.w = f2bf(f.w);
  return s;
}

// DPP row_shr:N add step; after N=8,4,2,1 lane 15 of each row = row sum.
template<int CTRL>
__device__ __forceinline__ float dpp_add_step(float v){
  int x = __builtin_amdgcn_update_dpp(0, __float_as_int(v), CTRL, 0xf, 0xf, true);
  return v + __int_as_float(x);
}

// ---------------------------------------------------------------------------
// Weight pre-conversion: w_in (768x256) and w_o1 (256x256) fp32 -> bf16.
// 65536 threads x 4 elems; branch is wave-aligned (49152 % 64 == 0).
// ---------------------------------------------------------------------------
__global__ __launch_bounds__(256)
void cvt_w_k(const float* __restrict__ w_in, const float* __restrict__ w_o1,
             short* __restrict__ w_in_b, short* __restrict__ w_o1_b)
{
  int i = blockIdx.x * 256 + threadIdx.x;     // 0..65535
  if (i < 49152) {
    float4 q = *(const float4*)&w_in[i * 4];
    *(short4*)&w_in_b[i * 4] = f4_to_bf4(q);
  } else {
    int j = i - 49152;                        // 0..16383
    float4 q = *(const float4*)&w_o1[j * 4];
    *(short4*)&w_o1_b[j * 4] = f4_to_bf4(q);
  }
}

// ---------------------------------------------------------------------------
// MFMA bf16 GEMM. Grid (m-tiles, n-tiles): m on blockIdx.x (XCD L2 reuse).
// A: fp32 (ABF=0, converted in staging) or bf16 (ABF=1, pure 16B copy).
// Bw: bf16 (pre-converted) -> staging is a pure 16B copy.
// EPI 0: plain store. EPI 2: (acc * zc[m,n] * cwx[n] + bias[n]) (zc bf16).
// ---------------------------------------------------------------------------
template<int EPI, bool ABF, bool OBF>
__global__ __launch_bounds__(256)
void mfma_gemm_k(const void* __restrict__ Av, const short* __restrict__ Bw,
                 void* __restrict__ Outv, int N, int K,
                 const float* __restrict__ bias, const short* __restrict__ zc,
                 const float* __restrict__ cwx)
{
  constexpr int BM = 128, BN = 128, BK = 32, LDP = 40;  // pad 32->40 shorts
  __shared__ short As[BM * LDP];
  __shared__ short Bs[BN * LDP];
  const int tid  = threadIdx.x;
  const int wave = tid >> 6, lane = tid & 63;
  const int quad = lane >> 4, l16 = lane & 15;
  const int wm = (wave & 1) * 64, wn = (wave >> 1) * 64;
  const int m0 = blockIdx.x * BM, n0 = blockIdx.y * BN;
  const int srow = tid >> 3;            // fp32-A path: 0..31
  const int skq  = (tid & 7) * 4;       // fp32-A path: 0,4,..,28
  const int crow = tid >> 2;            // bf16 copy path: 0..63
  const int cck  = (tid & 3) * 8;       // bf16 copy path: 0,8,16,24

  f32x4 acc[4][4] = {};

  for (int k0 = 0; k0 < K; k0 += BK) {
    if constexpr (ABF) {                // A bf16: pure 16B copy, 2 passes
      #pragma unroll
      for (int p = 0; p < 2; p++) {
        int row = p * 64 + crow;
        uint4 v = *(const uint4*)((const short*)Av + (size_t)(m0 + row) * K + k0 + cck);
        *(uint4*)&As[row * LDP + cck] = v;
      }
    } else {                            // A fp32: load + cvt, 4 passes
      #pragma unroll
      for (int p = 0; p < 4; p++) {
        int row = p * 32 + srow;
        size_t ga = (size_t)(m0 + row) * K + k0 + skq;
        float4 q = *(const float4*)((const float*)Av + ga);
        *(short4*)&As[row * LDP + skq] = f4_to_bf4(q);
      }
    }
    { // B bf16: pure 16B copy, 2 passes
      #pragma unroll
      for (int p = 0; p < 2; p++) {
        int row = p * 64 + crow;
        uint4 v = *(const uint4*)(Bw + (size_t)(n0 + row) * K + k0 + cck);
        *(uint4*)&Bs[row * LDP + cck] = v;
      }
    }
    __syncthreads();
    bf16x8 fa[4], fb[4];
    #pragma unroll
    for (int i = 0; i < 4; i++) {
      fa[i] = *(const bf16x8*)&As[(wm + i * 16 + l16) * LDP + quad * 8];
      fb[i] = *(const bf16x8*)&Bs[(wn + i * 16 + l16) * LDP + quad * 8];
    }
    #pragma unroll
    for (int i = 0; i < 4; i++)
      #pragma unroll
      for (int j = 0; j < 4; j++)
        acc[i][j] = __builtin_amdgcn_mfma_f32_16x16x32_bf16(fa[i], fb[j], acc[i][j], 0, 0, 0);
    __syncthreads();
  }

  #pragma unroll
  for (int i = 0; i < 4; i++) {
    #pragma unroll
    for (int j = 0; j < 4; j++) {
      int n = n0 + wn + j * 16 + l16;
      #pragma unroll
      for (int r = 0; r < 4; r++) {
        int m = m0 + wm + i * 16 + quad * 4 + r;
        float v = acc[i][j][r];
        if constexpr (EPI == 2)
          v = v * bf2f(zc[(size_t)m * N + n]) * cwx[n] + bias[n];
        if constexpr (OBF) ((short*)Outv)[(size_t)m * N + n] = f2bf(v);
        else               ((float*)Outv)[(size_t)m * N + n] = v;
      }
    }
  }
}

// ---------------------------------------------------------------------------
// Fused K3+K4 (TM=32, grid MT/32 = 512 -> 2 blocks/CU for latency hiding):
// phase 1 xdbl[M,48] = xc @ x_proj_w^T (A bf16), dt_r cols kept in LDS;
// phase 2 dtv[M,256] = softplus(dt_r @ dt_proj_w^T + 2*b_dt).
// ---------------------------------------------------------------------------
__global__ __launch_bounds__(256)
void gemm34_k(const short* __restrict__ xcb,   // (MT,256) bf16
              const float* __restrict__ Bw,    // x_proj_w (48,256) fp32
              const float* __restrict__ wdt,   // dt_proj_w (256,16)
              const float* __restrict__ bdt,   // dt_proj_b (256)
              float* __restrict__ xdbl,        // (MT,48)
              float* __restrict__ dtv)         // (MT,256)
{
  constexpr int TM = 32, TK = 16, NN = 48;
  __shared__ __align__(16) float As[TK][TM + 4];
  __shared__ __align__(16) float Bs[TK][64 + 4];
  __shared__ __align__(16) float dt_s[TM][20];
  __shared__ __align__(16) float wdt_s[256][20];
  const int tid = threadIdx.x;
  const int tn = tid & 15, tm = tid >> 4;      // tm 0..15 (2 rows each)
  const int m0 = blockIdx.x * TM;
  float acc[2][4] = {};
  const int mlA = tid >> 3, kdA = (tid & 7) * 2;   // A: 32 rows x 2 shorts
  const int mlB = tid >> 2, kqB = (tid & 3) * 4;   // B: 64 rows x 4 floats

  { // stage w_dt (256x16) -> LDS, one row per thread
    float4 q0 = *(const float4*)&wdt[tid * 16 + 0];
    float4 q1 = *(const float4*)&wdt[tid * 16 + 4];
    float4 q2 = *(const float4*)&wdt[tid * 16 + 8];
    float4 q3 = *(const float4*)&wdt[tid * 16 + 12];
    *(float4*)&wdt_s[tid][0]  = q0;
    *(float4*)&wdt_s[tid][4]  = q1;
    *(float4*)&wdt_s[tid][8]  = q2;
    *(float4*)&wdt_s[tid][12] = q3;
  }

  for (int k0 = 0; k0 < 256; k0 += TK) {
    {
      size_t off = (size_t)(m0 + mlA) * 256 + k0 + kdA;
      unsigned int v = *(const unsigned int*)(xcb + off);
      As[kdA + 0][mlA] = bf2f((short)(v & 0xffffu));
      As[kdA + 1][mlA] = bf2f((short)(v >> 16));
    }
    {
      float v0 = 0.f, v1 = 0.f, v2 = 0.f, v3 = 0.f;
      if (mlB < NN) {
        float4 q = *(const float4*)(Bw + (size_t)mlB * 256 + k0 + kqB);
        v0 = q.x; v1 = q.y; v2 = q.z; v3 = q.w;
      }
      Bs[kqB+0][mlB] = v0; Bs[kqB+1][mlB] = v1; Bs[kqB+2][mlB] = v2; Bs[kqB+3][mlB] = v3;
    }
    __syncthreads();
    #pragma unroll
    for (int k = 0; k < TK; k++) {
      float2 av = *(const float2*)&As[k][tm << 1];
      float4 bv = *(const float4*)&Bs[k][tn << 2];
      float a[2] = {av.x, av.y};
      float b[4] = {bv.x, bv.y, bv.z, bv.w};
      #pragma unroll
      for (int i = 0; i < 2; i++)
        #pragma unroll
        for (int j = 0; j < 4; j++)
          acc[i][j] = fmaf(a[i], b[j], acc[i][j]);
    }
    __syncthreads();
  }

  #pragma unroll
  for (int i = 0; i < 2; i++) {
    int m = m0 + (tm << 1) + i;
    #pragma unroll
    for (int j = 0; j < 4; j++) {
      int n = (tn << 2) + j;
      float v = acc[i][j];
      if (n < NN) xdbl[(size_t)m * NN + n] = v;
      if (tn < 4) dt_s[(tm << 1) + i][n] = v;   // dt_r cols 0..15
    }
  }
  __syncthreads();

  // phase 2: dtv[32 x 256] = softplus(dt_s @ wdt_s^T + 2*bdt)
  const int c0 = tid & 63, rg = tid >> 6;
  float w[4][16];
  float bb[4];
  #pragma unroll
  for (int cc = 0; cc < 4; cc++) {
    int col = cc * 64 + c0;
    #pragma unroll
    for (int q = 0; q < 4; q++) {
      float4 t = *(const float4*)&wdt_s[col][q * 4];
      w[cc][q*4+0] = t.x; w[cc][q*4+1] = t.y; w[cc][q*4+2] = t.z; w[cc][q*4+3] = t.w;
    }
    bb[cc] = 2.f * bdt[col];
  }
  #pragma unroll
  for (int rr = 0; rr < 8; rr++) {
    int row = rg * 8 + rr;
    float dr[16];
    #pragma unroll
    for (int q = 0; q < 4; q++) {
      float4 t = *(const float4*)&dt_s[row][q * 4];
      dr[q*4+0] = t.x; dr[q*4+1] = t.y; dr[q*4+2] = t.z; dr[q*4+3] = t.w;
    }
    #pragma unroll
    for (int cc = 0; cc < 4; cc++) {
      float s = bb[cc];
      #pragma unroll
      for (int k = 0; k < 16; k++) s = fmaf(dr[k], w[cc][k], s);
      dtv[(size_t)(m0 + row) * 256 + cc * 64 + c0] = softplus_f(s);
    }
  }
}

// ---------------------------------------------------------------------------
// Depthwise conv + SiLU, register-sliding-window, bf16 in / bf16 out.
// ---------------------------------------------------------------------------
__global__ __launch_bounds__(256)
void conv_silu_k(const short* __restrict__ xyzb,   // (MT, 768) bf16
                 const float* __restrict__ wx, const float* __restrict__ bx,
                 const float* __restrict__ wy, const float* __restrict__ by,
                 const float* __restrict__ wz, const float* __restrict__ bz,
                 short* __restrict__ xcb, short* __restrict__ ycb,
                 short* __restrict__ zcb)
{
  int idx = blockIdx.x * 256 + threadIdx.x;     // over (MT/CT)*192
  int c4 = idx % 192;
  int lt = idx / 192;
  int row0 = lt * CT;
  int l0 = row0 & (SEQ - 1);

  float4 win[CT + 4];
  #pragma unroll
  for (int i = 0; i < CT + 4; i++) {
    int l = l0 + i - 2;
    if (l >= 0 && l < SEQ)
      win[i] = bf4_to_f4(*(const uint2*)(xyzb + (size_t)(row0 + i - 2) * 768 + c4 * 4));
    else
      win[i] = make_float4(0.f, 0.f, 0.f, 0.f);
  }

  if (c4 < 64) {                                 // x: k=1 pointwise
    int d = c4 * 4;
    float4 w  = *(const float4*)&wx[d];
    float4 bb = *(const float4*)&bx[d];
    #pragma unroll
    for (int t = 0; t < CT; t++) {
      float4 v = win[t + 2], o;
      o.x = silu_f(fmaf(v.x, w.x, bb.x));
      o.y = silu_f(fmaf(v.y, w.y, bb.y));
      o.z = silu_f(fmaf(v.z, w.z, bb.z));
      o.w = silu_f(fmaf(v.w, w.w, bb.w));
      *(short4*)&xcb[(size_t)(row0 + t) * 256 + d] = f4_to_bf4(o);
    }
  } else if (c4 < 128) {                         // y: k=3
    int d = (c4 - 64) * 4;
    float wq[4][3];
    #pragma unroll
    for (int q = 0; q < 4; q++)
      #pragma unroll
      for (int j = 0; j < 3; j++) wq[q][j] = wy[(d + q) * 3 + j];
    float4 bb = *(const float4*)&by[d];
    #pragma unroll
    for (int t = 0; t < CT; t++) {
      float a0 = bb.x, a1 = bb.y, a2 = bb.z, a3 = bb.w;
      #pragma unroll
      for (int j = 0; j < 3; j++) {
        float4 v = win[t + 1 + j];
        a0 = fmaf(v.x, wq[0][j], a0);
        a1 = fmaf(v.y, wq[1][j], a1);
        a2 = fmaf(v.z, wq[2][j], a2);
        a3 = fmaf(v.w, wq[3][j], a3);
      }
      float4 o; o.x = silu_f(a0); o.y = silu_f(a1); o.z = silu_f(a2); o.w = silu_f(a3);
      *(short4*)&ycb[(size_t)(row0 + t) * 256 + d] = f4_to_bf4(o);
    }
  } else {                                       // z: k=5
    int d = (c4 - 128) * 4;
    float wq[4][5];
    #pragma unroll
    for (int q = 0; q < 4; q++)
      #pragma unroll
      for (int j = 0; j < 5; j++) wq[q][j] = wz[(d + q) * 5 + j];
    float4 bb = *(const float4*)&bz[d];
    #pragma unroll
    for (int t = 0; t < CT; t++) {
      float a0 = bb.x, a1 = bb.y, a2 = bb.z, a3 = bb.w;
      #pragma unroll
      for (int j = 0; j < 5; j++) {
        float4 v = win[t + j];
        a0 = fmaf(v.x, wq[0][j], a0);
        a1 = fmaf(v.y, wq[1][j], a1);
        a2 = fmaf(v.z, wq[2][j], a2);
        a3 = fmaf(v.w, wq[3][j], a3);
      }
      float4 o; o.x = silu_f(a0); o.y = silu_f(a1); o.z = silu_f(a2); o.w = silu_f(a3);
      *(short4*)&zcb[(size_t)(row0 + t) * 256 + d] = f4_to_bf4(o);
    }
  }
}

// ---------------------------------------------------------------------------
// Chunked selective scan, t-unrolled x4, LDS transposed [channel][t].
// Pass C writeback now fuses the p*y elementwise product (reads ycb).
// ---------------------------------------------------------------------------
template<bool PASSC>
__global__ __launch_bounds__(256)
void scan_k(const short* __restrict__ xcb,    // u (bf16), (MT,256)
            const float* __restrict__ dtv,    // delta, (MT,256)
            const float* __restrict__ xdbl,   // (MT,48): [dt_r | B | C]
            const float* __restrict__ A_log,
            const float* __restrict__ Dp,
            const float* __restrict__ Hstart,
            float* __restrict__ Pbuf, float* __restrict__ hfbuf,
            const short* __restrict__ ycb,    // y-gate (bf16), pass C
            short* __restrict__ poutb)        // pass C out (bf16): (p)*yc
{
  __shared__ __align__(16) float2 du2_s[16 * 66];             // [ch][t]
  __shared__ __align__(16) float2 BC_s [PASSC ? 16 * 66 : 2]; // [n][t]
  __shared__ __align__(16) float  Bc_s [PASSC ? 4 : 16 * 68]; // [n][t] (pass A)
  __shared__ __align__(16) float  y_s  [PASSC ? 16 * 68 : 4]; // [ch][t]
  const int tid = threadIdx.x;
  const int n = tid & 15, dl = tid >> 4;
  const int ch = blockIdx.x;
  const int d0 = blockIdx.y * 16;
  const int b  = blockIdx.z;
  const int d  = d0 + dl;
  const int t0 = ch * LC;
  const size_t brow = (size_t)b * SEQ;

  float u_r[4];
  #pragma unroll
  for (int i = 0; i < 4; i++) {               // cooperative coalesced staging
    int t = (tid >> 4) + i * 16;
    int dd = tid & 15;
    size_t row = brow + t0 + t;
    float uval = bf2f(xcb[row * 256 + d0 + dd]);
    float dval = dtv[row * 256 + d0 + dd];
    du2_s[dd * 66 + t] = make_float2(dval, dval * uval);
    if constexpr (PASSC) {
      BC_s[dd * 66 + t] = make_float2(xdbl[row * 48 + 16 + dd],
                                      xdbl[row * 48 + 32 + dd]);
      u_r[i] = uval;
    } else {
      Bc_s[dd * 68 + t] = xdbl[row * 48 + 16 + dd];
    }
  }
  __syncthreads();

  const float A_dn = -__expf(A_log[d * NST + n]);
  const size_t cidx = (((size_t)b * DM + d) * NST + n) * NCHK + ch;

  float h = PASSC ? Hstart[cidx] : 0.f;
  float P = 1.f;
  for (int t4 = 0; t4 < LC; t4 += 4) {
    float4 a = *(const float4*)&du2_s[dl * 66 + t4];      // {dt0,du0,dt1,du1}
    float4 c = *(const float4*)&du2_s[dl * 66 + t4 + 2];  // {dt2,du2,dt3,du3}
    float dA[4], du[4];
    dA[0] = __expf(a.x * A_dn); du[0] = a.y;
    dA[1] = __expf(a.z * A_dn); du[1] = a.w;
    dA[2] = __expf(c.x * A_dn); du[2] = c.y;
    dA[3] = __expf(c.z * A_dn); du[3] = c.w;
    if constexpr (!PASSC) {
      float4 f = *(const float4*)&Bc_s[n * 68 + t4];      // B t4..t4+3
      float Bv[4] = {f.x, f.y, f.z, f.w};
      #pragma unroll
      for (int j = 0; j < 4; j++) {
        h = fmaf(dA[j], h, du[j] * Bv[j]);
        P *= dA[j];
      }
    } else {
      float4 e = *(const float4*)&BC_s[n * 66 + t4];      // {B0,C0,B1,C1}
      float4 g = *(const float4*)&BC_s[n * 66 + t4 + 2];  // {B2,C2,B3,C3}
      float Bv[4] = {e.x, e.z, g.x, g.z};
      float Cv[4] = {e.y, e.w, g.y, g.w};
      float yv[4];
      #pragma unroll
      for (int j = 0; j < 4; j++) {
        h = fmaf(dA[j], h, du[j] * Bv[j]);
        yv[j] = h * Cv[j];
      }
      #pragma unroll
      for (int j = 0; j < 4; j++) yv[j] = dpp_add_step<0x118>(yv[j]); // shr8
      #pragma unroll
      for (int j = 0; j < 4; j++) yv[j] = dpp_add_step<0x114>(yv[j]); // shr4
      #pragma unroll
      for (int j = 0; j < 4; j++) yv[j] = dpp_add_step<0x112>(yv[j]); // shr2
      #pragma unroll
      for (int j = 0; j < 4; j++) yv[j] = dpp_add_step<0x111>(yv[j]); // shr1
      if (n == 15)
        *(float4*)&y_s[dl * 68 + t4] = make_float4(yv[0], yv[1], yv[2], yv[3]);
    }
  }

  if constexpr (!PASSC) {
    Pbuf[cidx] = P;
    hfbuf[cidx] = h;
  } else {
    __syncthreads();
    const float Dval = Dp[d0 + n];
    #pragma unroll
    for (int i = 0; i < 4; i++) {             // coalesced writeback, fused *yc
      int t = (tid >> 4) + i * 16;
      size_t row = brow + t0 + t;
      float p = fmaf(Dval, u_r[i], y_s[n * 68 + t]);
      float yg = bf2f(ycb[row * 256 + d0 + n]);
      poutb[row * 256 + d0 + n] = f2bf(p * yg);
    }
  }
}

// serial combine across the 64 chunks; one thread per (b,d,n) chain
__global__ __launch_bounds__(256)
void scan_mid_k(const float* __restrict__ Pbuf, const float* __restrict__ hfbuf,
                float* __restrict__ Hstart)
{
  int tid = blockIdx.x * 256 + threadIdx.x;   // 0..16383
  size_t base = (size_t)tid * NCHK;
  float H = 0.f;
  for (int c = 0; c < NCHK; c++) {
    Hstart[base + c] = H;
    H = Pbuf[base + c] * H + hfbuf[base + c];
  }
}

// ---------------------------------------------------------------------------
extern "C" void kernel_launch(void* const* d_in, const int* in_sizes, int n_in,
                              void* d_out, int out_size, void* d_ws, size_t ws_size,
                              hipStream_t stream)
{
  const float* hs    = (const float*)d_in[0];
  const float* w_in  = (const float*)d_in[1];
  const float* w_xp  = (const float*)d_in[2];
  const float* w_dt  = (const float*)d_in[3];
  const float* b_dt  = (const float*)d_in[4];
  const float* A_log = (const float*)d_in[5];
  const float* Dp    = (const float*)d_in[6];
  const float* w_o1  = (const float*)d_in[7];
  const float* cwx   = (const float*)d_in[8];
  const float* cbx   = (const float*)d_in[9];
  const float* cwy   = (const float*)d_in[10];
  const float* cby   = (const float*)d_in[11];
  const float* cwz   = (const float*)d_in[12];
  const float* cbz   = (const float*)d_in[13];

  char* wsb = (char*)d_ws;
  short* xyzb = (short*)wsb;                            // MT*768 bf16
  short* xcb  = (short*)(wsb + (size_t)MT * 768 * 2);   // MT*256 bf16
  short* ycb  = xcb + (size_t)MT * 256;                 // MT*256 bf16
  short* zcb  = ycb + (size_t)MT * 256;                 // MT*256 bf16
  short* pbufb= zcb + (size_t)MT * 256;                 // MT*256 bf16 (p*yc)
  short* w_in_b = pbufb + (size_t)MT * 256;             // 768*256 bf16
  short* w_o1_b = w_in_b + 768 * 256;                   // 256*256 bf16
  float* xdbl = (float*)(w_o1_b + 256 * 256 + 128);     // MT*48 fp32
  float* dtv  = xdbl + (size_t)MT * 48;                 // MT*256 fp32
  float* Pb   = dtv  + (size_t)MT * 256;                // 1M fp32
  float* hf   = Pb   + (size_t)B_SZ * DM * NST * NCHK;
  float* Hs   = hf   + (size_t)B_SZ * DM * NST * NCHK;

  dim3 blk(256);

  // K0: weights -> bf16
  cvt_w_k<<<dim3(256), blk, 0, stream>>>(w_in, w_o1, w_in_b, w_o1_b);

  // K1: xyz = hs @ in_proj_w^T  (bf16 MFMA, bf16 out; m-major grid)
  mfma_gemm_k<0, false, true><<<dim3(MT / 128, 768 / 128), blk, 0, stream>>>(
      hs, w_in_b, xyzb, 768, 256, nullptr, nullptr, nullptr);

  // K2: depthwise conv + SiLU -> xcb, ycb, zcb (bf16)
  conv_silu_k<<<dim3((MT / CT) * 192 / 256), blk, 0, stream>>>(
      xyzb, cwx, cbx, cwy, cby, cwz, cbz, xcb, ycb, zcb);

  // K3+K4 fused (TM=32, 512 blocks)
  gemm34_k<<<dim3(MT / 32), blk, 0, stream>>>(
      xcb, w_xp, w_dt, b_dt, xdbl, dtv);

  // K5-7: chunked selective scan -> pbufb = (scan out)*yc (bf16)
  scan_k<false><<<dim3(NCHK, DM / 16, B_SZ), blk, 0, stream>>>(
      xcb, dtv, xdbl, A_log, Dp, nullptr, Pb, hf, nullptr, nullptr);
  scan_mid_k<<<dim3((B_SZ * DM * NST) / 256), blk, 0, stream>>>(Pb, hf, Hs);
  scan_k<true><<<dim3(NCHK, DM / 16, B_SZ), blk, 0, stream>>>(
      xcb, dtv, xdbl, A_log, Dp, Hs, nullptr, nullptr, ycb, pbufb);

  // K8: out = (pbufb @ out_proj1_w^T) * zc * cwx + cbx  (fp32 out)
  mfma_gemm_k<2, true, false><<<dim3(MT / 128, 256 / 128), blk, 0, stream>>>(
      pbufb, w_o1_b, d_out, 256, 256, cbx, zcb, cwx);
}